// Round 10
// baseline (499.521 us; speedup 1.0000x reference)
//
#include <hip/hip_runtime.h>
#include <hip/hip_bf16.h>

#define N_NODES 8192
#define N_EDGES 65536
#define OUT0_ELEMS ((size_t)N_NODES * 1024)

using bf16 = __hip_bfloat16;
typedef __attribute__((ext_vector_type(8))) short short8;
typedef __attribute__((ext_vector_type(4))) float f32x4;

__device__ __forceinline__ float b2f(bf16 x) { return __bfloat162float(x); }
__device__ __forceinline__ bf16 f2b(float x) { return __float2bfloat16(x); }
__device__ __forceinline__ unsigned short bbits(float x)
{
  union { bf16 h; unsigned short u; } v; v.h = f2b(x); return v.u;
}
__device__ __forceinline__ unsigned pack2(float a, float b)
{
  return (unsigned)bbits(a) | ((unsigned)bbits(b) << 16);
}
__device__ __forceinline__ float4 cvt2x(uint2 u)
{
  float4 r;
  r.x = __uint_as_float(u.x << 16);
  r.y = __uint_as_float(u.x & 0xffff0000u);
  r.z = __uint_as_float(u.y << 16);
  r.w = __uint_as_float(u.y & 0xffff0000u);
  return r;
}
__device__ __forceinline__ float4 ld4b(const bf16* p)
{
  uint2 u = *(const uint2*)p;
  return cvt2x(u);
}
__device__ __forceinline__ void st4b(bf16* p, float a, float b, float c, float d)
{
  uint2 v; v.x = pack2(a, b); v.y = pack2(c, d);
  *(uint2*)p = v;
}

// Async global->LDS, 16B per lane: LDS dest = base + lane*16 (wave-uniform
// base), global src per-lane. Requires linear LDS tiles (guide m97/m104).
__device__ __forceinline__ void gll16(const bf16* g, short* l)
{
  __builtin_amdgcn_global_load_lds(
      (const __attribute__((address_space(1))) void*)g,
      (__attribute__((address_space(3))) void*)l, 16, 0, 0);
}

// Kept so any harness-side reference to the stub symbol still resolves.
__global__ void GNN_27650999451833_kernel() {}

__global__ void gnn6_zero(int* __restrict__ p, int n)
{
  int i = blockIdx.x * blockDim.x + threadIdx.x;
  if (i < n) p[i] = 0;
}

//---------------------------------------------------------------------
// f32 -> bf16 bulk convert (8 elems/thread)
//---------------------------------------------------------------------
__global__ __launch_bounds__(256)
void gnn7_cvt(const float* __restrict__ src, bf16* __restrict__ dst, int n8)
{
  int i = blockIdx.x * blockDim.x + threadIdx.x;
  if (i < n8) {
    float4 a = ((const float4*)src)[2 * i];
    float4 b = ((const float4*)src)[2 * i + 1];
    uint4 p;
    p.x = pack2(a.x, a.y); p.y = pack2(a.z, a.w);
    p.z = pack2(b.x, b.y); p.w = pack2(b.z, b.w);
    ((uint4*)dst)[i] = p;
  }
}

//---------------------------------------------------------------------
// w2v[8192,300](f32) -> w2v_pad[8192,320](bf16, cols>=300 zero)
//---------------------------------------------------------------------
__global__ __launch_bounds__(256)
void gnn8_pad_w2v(const float* __restrict__ src, bf16* __restrict__ dst)
{
  int idx = blockIdx.x * blockDim.x + threadIdx.x;
  if (idx >= N_NODES * 80) return;
  int r = idx / 80, c0 = (idx % 80) * 4;
  float v[4];
#pragma unroll
  for (int j = 0; j < 4; ++j) {
    int c = c0 + j;
    v[j] = (c < 300) ? src[(size_t)r * 300 + c] : 0.f;
  }
  uint2 p; p.x = pack2(v[0], v[1]); p.y = pack2(v[2], v[3]);
  *(uint2*)(dst + (size_t)r * 320 + c0) = p;
}

//---------------------------------------------------------------------
// WeTtail[1024][32](bf16): row c, k<16 = We[1024+k][c], else 0
//---------------------------------------------------------------------
__global__ __launch_bounds__(256)
void gnn12_t_Wetail(const float* __restrict__ We, bf16* __restrict__ BT)
{
  int c = blockIdx.x * 256 + threadIdx.x;
  if (c >= 1024) return;
  bf16* row = BT + (size_t)c * 32;
#pragma unroll
  for (int k = 0; k < 16; ++k)
    row[k] = f2b(We[(size_t)(1024 + k) * 1024 + c]);
#pragma unroll
  for (int k = 16; k < 32; ++k) row[k] = f2b(0.f);
}

//---------------------------------------------------------------------
// Transposed weight prepacks (LDS 32x32 tile transpose, 256 thr = 32x8)
//---------------------------------------------------------------------
// WeT[2048][1024] <- We_eff[k][n] = n<1024 ? We[k][n] : We[1040+k][n-1024]
__global__ __launch_bounds__(256)
void gnn10_t_We(const float* __restrict__ src, bf16* __restrict__ dst)
{
  __shared__ float tile[32][33];
  const int kb = blockIdx.x * 32, nb = blockIdx.y * 32;
  const int tx = threadIdx.x & 31, ty = threadIdx.x >> 5;
  const int n = nb + tx;
#pragma unroll
  for (int i = ty; i < 32; i += 8)
    tile[i][tx] = (n < 1024)
        ? src[(size_t)(kb + i) * 1024 + n]
        : src[(size_t)(1040 + kb + i) * 1024 + (n - 1024)];
  __syncthreads();
#pragma unroll
  for (int i = ty; i < 32; i += 8)
    dst[(size_t)(nb + i) * 1024 + kb + tx] = f2b(tile[tx][i]);
}

// WnT[1024][2048] <- Wn[k][n], k<2048, n<1024
__global__ __launch_bounds__(256)
void gnn10_t_Wn(const float* __restrict__ src, bf16* __restrict__ dst)
{
  __shared__ float tile[32][33];
  const int kb = blockIdx.x * 32, nb = blockIdx.y * 32;
  const int tx = threadIdx.x & 31, ty = threadIdx.x >> 5;
#pragma unroll
  for (int i = ty; i < 32; i += 8)
    tile[i][tx] = src[(size_t)(kb + i) * 1024 + nb + tx];
  __syncthreads();
#pragma unroll
  for (int i = ty; i < 32; i += 8)
    dst[(size_t)(nb + i) * 2048 + kb + tx] = f2b(tile[tx][i]);
}

// WelT_pad[1280][320] <- k<300 ? (n<600?Wel[k][n] : n<1200?Wel[300+k][n-600]:0):0
__global__ __launch_bounds__(256)
void gnn10_t_Wel(const float* __restrict__ src, bf16* __restrict__ dst)
{
  __shared__ float tile[32][33];
  const int kb = blockIdx.x * 32, nb = blockIdx.y * 32;
  const int tx = threadIdx.x & 31, ty = threadIdx.x >> 5;
  const int n = nb + tx;
#pragma unroll
  for (int i = ty; i < 32; i += 8) {
    int k = kb + i;
    float v = 0.f;
    if (k < 300) {
      if (n < 600)       v = src[(size_t)k * 600 + n];
      else if (n < 1200) v = src[(size_t)(300 + k) * 600 + (n - 600)];
    }
    tile[i][tx] = v;
  }
  __syncthreads();
#pragma unroll
  for (int i = ty; i < 32; i += 8)
    dst[(size_t)(nb + i) * 320 + kb + tx] = f2b(tile[tx][i]);
}

// WnlT_pad[384][640] <- kr(k)=k<300?k : 320<=k<620?k-20 : -1 ; n<300
__global__ __launch_bounds__(256)
void gnn10_t_Wnl(const float* __restrict__ src, bf16* __restrict__ dst)
{
  __shared__ float tile[32][33];
  const int kb = blockIdx.x * 32, nb = blockIdx.y * 32;
  const int tx = threadIdx.x & 31, ty = threadIdx.x >> 5;
  const int n = nb + tx;
#pragma unroll
  for (int i = ty; i < 32; i += 8) {
    int k = kb + i;
    int kr = (k < 300) ? k : ((k >= 320 && k < 620) ? (k - 20) : -1);
    tile[i][tx] = (kr >= 0 && n < 300) ? src[(size_t)kr * 300 + n] : 0.f;
  }
  __syncthreads();
#pragma unroll
  for (int i = ty; i < 32; i += 8)
    dst[(size_t)(nb + i) * 640 + kb + tx] = f2b(tile[tx][i]);
}

//---------------------------------------------------------------------
// MFMA GEMM v17: global_load_lds-staged. Linear LDS [128][32]/operand.
//---------------------------------------------------------------------
// P[8192,2048] = nf_bf[8192,1024] @ WeT^T ; if be: fold be into cols>=1024
__global__ __launch_bounds__(256)
void gnn17_mm_P(const bf16* __restrict__ A, const bf16* __restrict__ BT,
                bf16* __restrict__ P, const float* __restrict__ be)
{
  __shared__ short As[128 * 32];
  __shared__ short Bs[128 * 32];
  const int t = threadIdx.x;
  const int col0 = blockIdx.x * 128, row0 = blockIdx.y * 128;
  const int lane = t & 63, w = t >> 6, m16 = lane & 15, q = lane >> 4;
  const int wr = w >> 1, wc = w & 1;

  f32x4 acc[4][4];
#pragma unroll
  for (int mi = 0; mi < 4; ++mi)
#pragma unroll
    for (int ni = 0; ni < 4; ++ni) acc[mi][ni] = (f32x4){0.f, 0.f, 0.f, 0.f};

  const int glr = w * 16 + (lane >> 2);
  const int glc = (lane & 3) * 8;
  short* lA0 = &As[w * 512];
  short* lA1 = &As[2048 + w * 512];
  short* lB0 = &Bs[w * 512];
  short* lB1 = &Bs[2048 + w * 512];
  const bf16* ar0 = A + (size_t)(row0 + glr) * 1024 + glc;
  const bf16* ar1 = A + (size_t)(row0 + 64 + glr) * 1024 + glc;
  const bf16* br0 = BT + (size_t)(col0 + glr) * 1024 + glc;
  const bf16* br1 = BT + (size_t)(col0 + 64 + glr) * 1024 + glc;

  for (int k0 = 0; k0 < 1024; k0 += 32) {
    if (k0) __syncthreads();
    gll16(ar0 + k0, lA0);
    gll16(ar1 + k0, lA1);
    gll16(br0 + k0, lB0);
    gll16(br1 + k0, lB1);
    __syncthreads();
    short8 af[4];
#pragma unroll
    for (int mi = 0; mi < 4; ++mi)
      af[mi] = *(const short8*)&As[(wr * 64 + mi * 16 + m16) * 32 + 8 * q];
#pragma unroll
    for (int ni = 0; ni < 4; ++ni) {
      short8 bfv = *(const short8*)&Bs[(wc * 64 + ni * 16 + m16) * 32 + 8 * q];
#pragma unroll
      for (int mi = 0; mi < 4; ++mi)
        acc[mi][ni] =
            __builtin_amdgcn_mfma_f32_16x16x32_bf16(af[mi], bfv, acc[mi][ni], 0, 0, 0);
    }
  }
#pragma unroll
  for (int mi = 0; mi < 4; ++mi)
#pragma unroll
    for (int ni = 0; ni < 4; ++ni) {
      int c = col0 + wc * 64 + ni * 16 + m16;
      float bias = (be != nullptr && c >= 1024) ? be[c - 1024] : 0.f;
#pragma unroll
      for (int r = 0; r < 4; ++r)
        P[(size_t)(row0 + wr * 64 + mi * 16 + 4 * q + r) * 2048 + c] =
            f2b(acc[mi][ni][r] + bias);
    }
}

// out0[8192,1024](f32) = relu([nf_bf | zf] @ WnT^T + bn), K=2048
__global__ __launch_bounds__(256)
void gnn17_mm_out_n(const bf16* __restrict__ A0, const bf16* __restrict__ A1,
                    const bf16* __restrict__ BT, const float* __restrict__ bn,
                    float* __restrict__ out)
{
  __shared__ short As[128 * 32];
  __shared__ short Bs[128 * 32];
  const int t = threadIdx.x;
  const int col0 = blockIdx.x * 128, row0 = blockIdx.y * 128;
  const int lane = t & 63, w = t >> 6, m16 = lane & 15, q = lane >> 4;
  const int wr = w >> 1, wc = w & 1;

  f32x4 acc[4][4];
#pragma unroll
  for (int mi = 0; mi < 4; ++mi)
#pragma unroll
    for (int ni = 0; ni < 4; ++ni) acc[mi][ni] = (f32x4){0.f, 0.f, 0.f, 0.f};

  const int glr = w * 16 + (lane >> 2);
  const int glc = (lane & 3) * 8;
  short* lA0 = &As[w * 512];
  short* lA1 = &As[2048 + w * 512];
  short* lB0 = &Bs[w * 512];
  short* lB1 = &Bs[2048 + w * 512];
  const bf16* br0 = BT + (size_t)(col0 + glr) * 2048 + glc;
  const bf16* br1 = BT + (size_t)(col0 + 64 + glr) * 2048 + glc;

  for (int k0 = 0; k0 < 2048; k0 += 32) {
    if (k0) __syncthreads();
    const bf16* ab = (k0 < 1024) ? A0 : A1;
    const int kk = (k0 < 1024) ? k0 : (k0 - 1024);
    gll16(ab + (size_t)(row0 + glr) * 1024 + kk + glc, lA0);
    gll16(ab + (size_t)(row0 + 64 + glr) * 1024 + kk + glc, lA1);
    gll16(br0 + k0, lB0);
    gll16(br1 + k0, lB1);
    __syncthreads();
    short8 af[4];
#pragma unroll
    for (int mi = 0; mi < 4; ++mi)
      af[mi] = *(const short8*)&As[(wr * 64 + mi * 16 + m16) * 32 + 8 * q];
#pragma unroll
    for (int ni = 0; ni < 4; ++ni) {
      short8 bfv = *(const short8*)&Bs[(wc * 64 + ni * 16 + m16) * 32 + 8 * q];
#pragma unroll
      for (int mi = 0; mi < 4; ++mi)
        acc[mi][ni] =
            __builtin_amdgcn_mfma_f32_16x16x32_bf16(af[mi], bfv, acc[mi][ni], 0, 0, 0);
    }
  }
#pragma unroll
  for (int mi = 0; mi < 4; ++mi)
#pragma unroll
    for (int ni = 0; ni < 4; ++ni) {
      int c = col0 + wc * 64 + ni * 16 + m16;
      float bias = bn[c];
#pragma unroll
      for (int r = 0; r < 4; ++r) {
        float v = acc[mi][ni][r] + bias;
        out[(size_t)(row0 + wr * 64 + mi * 16 + 4 * q + r) * 1024 + c] =
            fmaxf(v, 0.f);
      }
    }
}

// Q[8192,1280](bf16) = w2v_pad[8192,320] @ WelT^T, K=320
// if bel: fold bel into cols [600,1200)
__global__ __launch_bounds__(256)
void gnn10_mm_Q(const bf16* __restrict__ A, const bf16* __restrict__ BT,
                bf16* __restrict__ Q, const float* __restrict__ bel)
{
  __shared__ short As[128 * 40];
  __shared__ short Bs[128 * 40];
  const int t = threadIdx.x;
  const int col0 = blockIdx.x * 128, row0 = blockIdx.y * 128;
  const int lane = t & 63, w = t >> 6, m16 = lane & 15, q = lane >> 4;
  const int wr = w >> 1, wc = w & 1;

  f32x4 acc[4][4];
#pragma unroll
  for (int mi = 0; mi < 4; ++mi)
#pragma unroll
    for (int ni = 0; ni < 4; ++ni) acc[mi][ni] = (f32x4){0.f, 0.f, 0.f, 0.f};

  const int ar = t >> 1, ah = (t & 1) * 16;
  const bf16* aptr = A + (size_t)(row0 + ar) * 320 + ah;
  const bf16* bptr = BT + (size_t)(col0 + ar) * 320 + ah;

  uint4 a0 = *(const uint4*)(aptr);
  uint4 a1 = *(const uint4*)(aptr + 8);
  uint4 b0 = *(const uint4*)(bptr);
  uint4 b1 = *(const uint4*)(bptr + 8);

  for (int k0 = 0; k0 < 320; k0 += 32) {
    if (k0) __syncthreads();
    *(uint4*)&As[ar * 40 + ah] = a0;
    *(uint4*)&As[ar * 40 + ah + 8] = a1;
    *(uint4*)&Bs[ar * 40 + ah] = b0;
    *(uint4*)&Bs[ar * 40 + ah + 8] = b1;
    __syncthreads();
    if (k0 + 32 < 320) {
      a0 = *(const uint4*)(aptr + k0 + 32);
      a1 = *(const uint4*)(aptr + k0 + 40);
      b0 = *(const uint4*)(bptr + k0 + 32);
      b1 = *(const uint4*)(bptr + k0 + 40);
    }
    short8 af[4];
#pragma unroll
    for (int mi = 0; mi < 4; ++mi)
      af[mi] = *(const short8*)&As[(wr * 64 + mi * 16 + m16) * 40 + 8 * q];
#pragma unroll
    for (int ni = 0; ni < 4; ++ni) {
      short8 bfv = *(const short8*)&Bs[(wc * 64 + ni * 16 + m16) * 40 + 8 * q];
#pragma unroll
      for (int mi = 0; mi < 4; ++mi)
        acc[mi][ni] =
            __builtin_amdgcn_mfma_f32_16x16x32_bf16(af[mi], bfv, acc[mi][ni], 0, 0, 0);
    }
  }
#pragma unroll
  for (int mi = 0; mi < 4; ++mi)
#pragma unroll
    for (int ni = 0; ni < 4; ++ni) {
      int c = col0 + wc * 64 + ni * 16 + m16;
      float bias = (bel != nullptr && c >= 600 && c < 1200) ? bel[c - 600] : 0.f;
#pragma unroll
      for (int r = 0; r < 4; ++r)
        Q[(size_t)(row0 + wr * 64 + mi * 16 + 4 * q + r) * 1280 + c] =
            f2b(acc[mi][ni][r] + bias);
    }
}

// out1[8192,300](f32) = relu([w2v_pad | zfl_pad] @ WnlT^T + bnl), K=640
__global__ __launch_bounds__(256)
void gnn10_mm_out_l(const bf16* __restrict__ A0, const bf16* __restrict__ A1,
                    const bf16* __restrict__ BT, const float* __restrict__ bnl,
                    float* __restrict__ out2)
{
  __shared__ short As[128 * 40];
  __shared__ short Bs[128 * 40];
  const int t = threadIdx.x;
  const int col0 = blockIdx.x * 128, row0 = blockIdx.y * 128;
  const int lane = t & 63, w = t >> 6, m16 = lane & 15, q = lane >> 4;
  const int wr = w >> 1, wc = w & 1;

  f32x4 acc[4][4];
#pragma unroll
  for (int mi = 0; mi < 4; ++mi)
#pragma unroll
    for (int ni = 0; ni < 4; ++ni) acc[mi][ni] = (f32x4){0.f, 0.f, 0.f, 0.f};

  const int ar = t >> 1, ah = (t & 1) * 16;
  const bf16* ap0 = A0 + (size_t)(row0 + ar) * 320 + ah;
  const bf16* ap1 = A1 + (size_t)(row0 + ar) * 320 + ah;
  const bf16* bptr = BT + (size_t)(col0 + ar) * 640 + ah;

  uint4 a0 = *(const uint4*)(ap0);
  uint4 a1 = *(const uint4*)(ap0 + 8);
  uint4 b0 = *(const uint4*)(bptr);
  uint4 b1 = *(const uint4*)(bptr + 8);

  for (int k0 = 0; k0 < 640; k0 += 32) {
    if (k0) __syncthreads();
    *(uint4*)&As[ar * 40 + ah] = a0;
    *(uint4*)&As[ar * 40 + ah + 8] = a1;
    *(uint4*)&Bs[ar * 40 + ah] = b0;
    *(uint4*)&Bs[ar * 40 + ah + 8] = b1;
    __syncthreads();
    if (k0 + 32 < 640) {
      int kn = k0 + 32;
      const bf16* ap = (kn < 320) ? (ap0 + kn) : (ap1 + (kn - 320));
      a0 = *(const uint4*)(ap);
      a1 = *(const uint4*)(ap + 8);
      b0 = *(const uint4*)(bptr + kn);
      b1 = *(const uint4*)(bptr + kn + 8);
    }
    short8 af[4];
#pragma unroll
    for (int mi = 0; mi < 4; ++mi)
      af[mi] = *(const short8*)&As[(wr * 64 + mi * 16 + m16) * 40 + 8 * q];
#pragma unroll
    for (int ni = 0; ni < 4; ++ni) {
      short8 bfv = *(const short8*)&Bs[(wc * 64 + ni * 16 + m16) * 40 + 8 * q];
#pragma unroll
      for (int mi = 0; mi < 4; ++mi)
        acc[mi][ni] =
            __builtin_amdgcn_mfma_f32_16x16x32_bf16(af[mi], bfv, acc[mi][ni], 0, 0, 0);
    }
  }
#pragma unroll
  for (int mi = 0; mi < 4; ++mi)
#pragma unroll
    for (int ni = 0; ni < 4; ++ni) {
      int c = col0 + wc * 64 + ni * 16 + m16;
      if (c < 300) {
        float bias = bnl[c];
#pragma unroll
        for (int r = 0; r < 4; ++r) {
          float v = acc[mi][ni][r] + bias;
          out2[(size_t)(row0 + wr * 64 + mi * 16 + 4 * q + r) * 300 + c] =
              fmaxf(v, 0.f);
        }
      }
    }
}

//---------------------------------------------------------------------
// CSR build (v14: fill also emits srcs/dsts in CSR order)
//---------------------------------------------------------------------
__global__ void gnn6_count(const int* __restrict__ dst, int* __restrict__ cnt)
{
  int e = blockIdx.x * blockDim.x + threadIdx.x;
  if (e < N_EDGES) atomicAdd(&cnt[dst[e]], 1);
}

__global__ __launch_bounds__(1024)
void gnn6_scan(const int* __restrict__ cnt, int* __restrict__ off, int* __restrict__ cur)
{
  __shared__ int sh[1024];
  const int t = threadIdx.x;
  int local[8]; int sum = 0;
#pragma unroll
  for (int i = 0; i < 8; ++i) { int v = cnt[t * 8 + i]; local[i] = sum; sum += v; }
  sh[t] = sum;
  __syncthreads();
  for (int d = 1; d < 1024; d <<= 1) {
    int v = (t >= d) ? sh[t - d] : 0;
    __syncthreads();
    sh[t] += v;
    __syncthreads();
  }
  int basev = (t > 0) ? sh[t - 1] : 0;
#pragma unroll
  for (int i = 0; i < 8; ++i) { int o = basev + local[i]; off[t * 8 + i] = o; cur[t * 8 + i] = o; }
  if (t == 1023) off[8192] = sh[1023];
}

__global__ void gnn6_fill(const int* __restrict__ dst, int* __restrict__ cur,
                          int* __restrict__ elist)
{
  int e = blockIdx.x * blockDim.x + threadIdx.x;
  if (e < N_EDGES) { int p = atomicAdd(&cur[dst[e]], 1); elist[p] = e; }
}

__global__ void gnn14_fill(const int* __restrict__ dst, const int* __restrict__ src,
                           int* __restrict__ cur, int* __restrict__ elist,
                           int* __restrict__ srcs, int* __restrict__ dsts)
{
  int e = blockIdx.x * blockDim.x + threadIdx.x;
  if (e < N_EDGES) {
    int d = dst[e];
    int p = atomicAdd(&cur[d], 1);
    elist[p] = e;
    srcs[p] = src[e];
    dsts[p] = d;
  }
}

// sfp[p][32](bf16) = padded s_f[elist[p]] — CSR-ordered edge features.
__global__ __launch_bounds__(256)
void gnn14_sfp(const float* __restrict__ s_f, const int* __restrict__ elist,
               bf16* __restrict__ sfp)
{
  int p = blockIdx.x * 256 + threadIdx.x;
  if (p >= N_EDGES) return;
  int e = elist[p];
  const float4* sp = (const float4*)(s_f + (size_t)e * 16);
  float4 s0 = sp[0], s1 = sp[1], s2 = sp[2], s3 = sp[3];
  uint4 lo, hi;
  lo.x = pack2(s0.x, s0.y); lo.y = pack2(s0.z, s0.w);
  lo.z = pack2(s1.x, s1.y); lo.w = pack2(s1.z, s1.w);
  hi.x = pack2(s2.x, s2.y); hi.y = pack2(s2.z, s2.w);
  hi.z = pack2(s3.x, s3.y); hi.w = pack2(s3.z, s3.w);
  uint4* dp = (uint4*)(sfp + (size_t)p * 32);
  dp[0] = lo; dp[1] = hi;
  dp[2] = (uint4){0, 0, 0, 0}; dp[3] = (uint4){0, 0, 0, 0};
}

//---------------------------------------------------------------------
// FUSED v18: like v14 (16 edges, S tile via MFMA into LDS + HBM) but
// phase 2 is a SINGLE pass over all 16 edges: 48 gather loads in one
// unrolled stream (deeper MLP), 16 parallel shuffle-reduce chains,
// 2 barriers total (v14 had 5). Same math, same outputs.
//---------------------------------------------------------------------
#define SLD_STRIDE 1032
__global__ __launch_bounds__(256)
void gnn18_score(const bf16* __restrict__ sfp, const bf16* __restrict__ WeTtail,
                 const int* __restrict__ srcs, const int* __restrict__ dsts,
                 const float* __restrict__ Wa, const float* __restrict__ ba,
                 const float* __restrict__ Wal, const float* __restrict__ bal,
                 const bf16* __restrict__ P, const bf16* __restrict__ Q,
                 bf16* __restrict__ S, float* __restrict__ af,
                 float* __restrict__ afl)
{
  __shared__ short Sld[16 * SLD_STRIDE];
  __shared__ float shf[16][4], shl[16][4];
  const int t = threadIdx.x;
  const int lane = t & 63, w = t >> 6, m16 = lane & 15, q = lane >> 4;
  const int p0 = blockIdx.x * 16;

  // ---- phase 1: S rows = sfp @ WeTtail^T (K=32), operand-swapped ----
  short8 bfr = *(const short8*)(sfp + (size_t)(p0 + m16) * 32 + 8 * q);
  const int cb = w * 256;
#pragma unroll
  for (int ni = 0; ni < 16; ++ni) {
    short8 afr = *(const short8*)(WeTtail + (size_t)(cb + ni * 16 + m16) * 32 + 8 * q);
    f32x4 acc = __builtin_amdgcn_mfma_f32_16x16x32_bf16(
        afr, bfr, (f32x4){0.f, 0.f, 0.f, 0.f}, 0, 0, 0);
    uint2 v; v.x = pack2(acc[0], acc[1]); v.y = pack2(acc[2], acc[3]);
    *(uint2*)&Sld[m16 * SLD_STRIDE + cb + ni * 16 + 4 * q] = v;
  }
  __syncthreads();

  // ---- write S tile to HBM (CSR-ordered rows; consumed by node_z) ----
  {
    const int row = t >> 4, cbase = (t & 15) * 8;
#pragma unroll
    for (int j = 0; j < 8; ++j) {
      uint4 v = *(const uint4*)&Sld[row * SLD_STRIDE + cbase + 128 * j];
      *(uint4*)(S + (size_t)(p0 + row) * 1024 + cbase + 128 * j) = v;
    }
  }

  // ---- phase 2: scores for all 16 edges, single pass ----
  const int c0 = 4 * t;
  float4 wav = *(const float4*)(Wa + c0);
  const bool lact = (t < 150);
  float4 walv = {0, 0, 0, 0};
  if (lact) walv = *(const float4*)(Wal + c0);
  const float ba0 = ba[0], bal0 = bal[0];

  int ss[16], dd[16];
  {
#pragma unroll
    for (int g = 0; g < 4; ++g) {
      int4 a4 = *(const int4*)(srcs + p0 + 4 * g);
      ss[4 * g] = a4.x; ss[4 * g + 1] = a4.y; ss[4 * g + 2] = a4.z; ss[4 * g + 3] = a4.w;
      int4 c4 = *(const int4*)(dsts + p0 + 4 * g);
      dd[4 * g] = c4.x; dd[4 * g + 1] = c4.y; dd[4 * g + 2] = c4.z; dd[4 * g + 3] = c4.w;
    }
  }

  float pf[16], pl[16];
#pragma unroll
  for (int i = 0; i < 16; ++i) {
    uint2 us = *(const uint2*)&Sld[i * SLD_STRIDE + c0];
    float4 sv = cvt2x(us);
    float4 p1 = ld4b(P + (size_t)ss[i] * 2048 + c0);
    float4 p2 = ld4b(P + (size_t)dd[i] * 2048 + 1024 + c0);
    float acc = 0.f;
    acc = fmaf(fmaxf(p1.x + p2.x + sv.x, 0.f), wav.x, acc);
    acc = fmaf(fmaxf(p1.y + p2.y + sv.y, 0.f), wav.y, acc);
    acc = fmaf(fmaxf(p1.z + p2.z + sv.z, 0.f), wav.z, acc);
    acc = fmaf(fmaxf(p1.w + p2.w + sv.w, 0.f), wav.w, acc);
    pf[i] = acc;

    float accl = 0.f;
    if (lact) {
      float4 q1 = ld4b(Q + (size_t)ss[i] * 1280 + c0);
      float4 q2 = ld4b(Q + (size_t)dd[i] * 1280 + 600 + c0);
      accl = fmaf(fmaxf(q1.x + q2.x, 0.f), walv.x, accl);
      accl = fmaf(fmaxf(q1.y + q2.y, 0.f), walv.y, accl);
      accl = fmaf(fmaxf(q1.z + q2.z, 0.f), walv.z, accl);
      accl = fmaf(fmaxf(q1.w + q2.w, 0.f), walv.w, accl);
    }
    pl[i] = accl;
  }

#pragma unroll
  for (int i = 0; i < 16; ++i) {
#pragma unroll
    for (int o = 32; o > 0; o >>= 1) {
      pf[i] += __shfl_down(pf[i], o, 64);
      pl[i] += __shfl_down(pl[i], o, 64);
    }
  }
  if (lane == 0) {
#pragma unroll
    for (int i = 0; i < 16; ++i) { shf[i][w] = pf[i]; shl[i][w] = pl[i]; }
  }
  __syncthreads();
  if (t < 16)
    af[p0 + t] = shf[t][0] + shf[t][1] + shf[t][2] + shf[t][3] + ba0;
  if (t >= 64 && t < 80) {
    const int i = t - 64;
    afl[p0 + i] = shl[i][0] + shl[i][1] + shl[i][2] + shl[i][3] + bal0;
  }
}

//---------------------------------------------------------------------
// Edge scores v11 (FALLBACK when workspace too small for S)
//---------------------------------------------------------------------
__global__ __launch_bounds__(256)
void gnn11_edge_score(const int* __restrict__ src, const int* __restrict__ dst,
                      const float* __restrict__ s_f, const float* __restrict__ We,
                      const float* __restrict__ be, const float* __restrict__ Wa,
                      const float* __restrict__ ba, const float* __restrict__ bel,
                      const float* __restrict__ Wal, const float* __restrict__ bal,
                      const bf16* __restrict__ P, const bf16* __restrict__ Q,
                      float* __restrict__ af, float* __restrict__ afl)
{
  const int t = threadIdx.x;
  const int lane = t & 63, w = t >> 6;
  const int c0 = 4 * t;
  const int e0 = blockIdx.x * 8;

  float wef[16][4];
#pragma unroll
  for (int k = 0; k < 16; ++k) {
    float4 v = *(const float4*)(We + (size_t)(1024 + k) * 1024 + c0);
    wef[k][0] = v.x; wef[k][1] = v.y; wef[k][2] = v.z; wef[k][3] = v.w;
  }
  float4 bev = *(const float4*)(be + c0);
  float4 wav = *(const float4*)(Wa + c0);
  const bool lact = (t < 150);
  float4 belv = {0, 0, 0, 0}, walv = {0, 0, 0, 0};
  if (lact) { belv = *(const float4*)(bel + c0); walv = *(const float4*)(Wal + c0); }

  int ss[8], dd[8];
  {
    int4 a = *(const int4*)(src + e0);
    int4 b = *(const int4*)(src + e0 + 4);
    ss[0] = a.x; ss[1] = a.y; ss[2] = a.z; ss[3] = a.w;
    ss[4] = b.x; ss[5] = b.y; ss[6] = b.z; ss[7] = b.w;
    int4 c = *(const int4*)(dst + e0);
    int4 d = *(const int4*)(dst + e0 + 4);
    dd[0] = c.x; dd[1] = c.y; dd[2] = c.z; dd[3] = c.w;
    dd[4] = d.x; dd[5] = d.y; dd[6] = d.z; dd[7] = d.w;
  }

  float pf[8], pl[8];

#pragma unroll
  for (int i = 0; i < 8; ++i) {
    const int e = e0 + i;
    float sfv[16];
    {
      const float4* sp = (const float4*)(s_f + (size_t)e * 16);
      float4 s0 = sp[0], s1 = sp[1], s2 = sp[2], s3 = sp[3];
      sfv[0] = s0.x; sfv[1] = s0.y; sfv[2] = s0.z; sfv[3] = s0.w;
      sfv[4] = s1.x; sfv[5] = s1.y; sfv[6] = s1.z; sfv[7] = s1.w;
      sfv[8] = s2.x; sfv[9] = s2.y; sfv[10] = s2.z; sfv[11] = s2.w;
      sfv[12] = s3.x; sfv[13] = s3.y; sfv[14] = s3.z; sfv[15] = s3.w;
    }
    float4 p1 = ld4b(P + (size_t)ss[i] * 2048 + c0);
    float4 p2 = ld4b(P + (size_t)dd[i] * 2048 + 1024 + c0);
    float pv[4] = {p1.x + p2.x + bev.x, p1.y + p2.y + bev.y,
                   p1.z + p2.z + bev.z, p1.w + p2.w + bev.w};
    float acc = 0.f;
#pragma unroll
    for (int j = 0; j < 4; ++j) {
      float v = pv[j];
#pragma unroll
      for (int k = 0; k < 16; ++k) v = fmaf(sfv[k], wef[k][j], v);
      acc = fmaf(fmaxf(v, 0.f), (&wav.x)[j], acc);
    }
    pf[i] = acc;

    float accl = 0.f;
    if (lact) {
      float4 q1 = ld4b(Q + (size_t)ss[i] * 1280 + c0);
      float4 q2 = ld4b(Q + (size_t)dd[i] * 1280 + 600 + c0);
      float qv[4] = {q1.x + q2.x + belv.x, q1.y + q2.y + belv.y,
                     q1.z + q2.z + belv.z, q1.w + q2.w + belv.w};
#pragma unroll
      for (int j = 0; j < 4; ++j)
        accl = fmaf(fmaxf(qv[j], 0.f), (&walv.x)[j], accl);
    }
    pl[i] = accl;
  }

  __shared__ float shf[8][4], shl[8][4];
#pragma unroll
  for (int i = 0; i < 8; ++i) {
#pragma unroll
    for (int o = 32; o > 0; o >>= 1) {
      pf[i] += __shfl_down(pf[i], o, 64);
      pl[i] += __shfl_down(pl[i], o, 64);
    }
  }
  if (lane == 0) {
#pragma unroll
    for (int i = 0; i < 8; ++i) { shf[i][w] = pf[i]; shl[i][w] = pl[i]; }
  }
  __syncthreads();
  if (t < 8)
    af[e0 + t] = shf[t][0] + shf[t][1] + shf[t][2] + shf[t][3] + ba[0];
  if (t >= 64 && t < 72) {
    const int i = t & 7;
    afl[e0 + i] = shl[i][0] + shl[i][1] + shl[i][2] + shl[i][3] + bal[0];
  }
}

//---------------------------------------------------------------------
// Per-node softmax. v14: position-indexed af/afl (sequential reads).
//---------------------------------------------------------------------
__global__ __launch_bounds__(256)
void gnn14_alpha(const int* __restrict__ off, float* __restrict__ af,
                 float* __restrict__ afl)
{
  const int n = blockIdx.x * 256 + threadIdx.x;
  if (n >= N_NODES) return;
  const int base = off[n];
  const int deg = off[n + 1] - base;
  float m = -1e30f, ml = -1e30f;
  for (int i = 0; i < deg; ++i) {
    m = fmaxf(m, af[base + i]);
    ml = fmaxf(ml, afl[base + i]);
  }
  float den = 0.f, denl = 0.f;
  for (int i = 0; i < deg; ++i) {
    den += expf(af[base + i] - m);
    denl += expf(afl[base + i] - ml);
  }
  float inv = (den > 0.f) ? 1.f / den : 0.f;
  float invl = (denl > 0.f) ? 1.f / denl : 0.f;
  for (int i = 0; i < deg; ++i) {
    af[base + i] = expf(af[base + i] - m) * inv;
    afl[base + i] = expf(afl[base + i] - ml) * invl;
  }
}

// v6 fallback (edge-id indexed via elist)
__global__ __launch_bounds__(256)
void gnn6_alpha(const int* __restrict__ off, const int* __restrict__ elist,
                float* __restrict__ af, float* __restrict__ afl)
{
  const int n = blockIdx.x * 256 + threadIdx.x;
  if (n >= N_NODES) return;
  const int base = off[n];
  const int deg = off[n + 1] - base;
  float m = -1e30f, ml = -1e30f;
  for (int i = 0; i < deg; ++i) {
    int e = elist[base + i];
    m = fmaxf(m, af[e]);
    ml = fmaxf(ml, afl[e]);
  }
  float den = 0.f, denl = 0.f;
  for (int i = 0; i < deg; ++i) {
    int e = elist[base + i];
    den += expf(af[e] - m);
    denl += expf(afl[e] - ml);
  }
  float inv = (den > 0.f) ? 1.f / den : 0.f;
  float invl = (denl > 0.f) ? 1.f / denl : 0.f;
  for (int i = 0; i < deg; ++i) {
    int e = elist[base + i];
    af[e] = expf(af[e] - m) * inv;
    afl[e] = expf(afl[e] - ml) * invl;
  }
}

//---------------------------------------------------------------------
// node_z v14: CSR-ordered — S rows, af/afl sequential; src via srcs.
//---------------------------------------------------------------------
__global__ __launch_bounds__(256)
void gnn14_node_z(const int* __restrict__ off, const int* __restrict__ srcs,
                  const float* __restrict__ af, const float* __restrict__ afl,
                  const bf16* __restrict__ nf_bf, const bf16* __restrict__ w2v_pad,
                  const bf16* __restrict__ S, const bf16* __restrict__ P,
                  bf16* __restrict__ zf, bf16* __restrict__ zfl_pad)
{
  const int node = blockIdx.x;
  const int t = threadIdx.x;
  const int c0 = 4 * t;
  const int base = off[node];
  const int deg = off[node + 1] - base;

  float4 p2v = ld4b(P + (size_t)node * 2048 + 1024 + c0);  // be folded in
  const float p2[4] = {p2v.x, p2v.y, p2v.z, p2v.w};

  float acc[4] = {0.f, 0.f, 0.f, 0.f};
  float accl[4] = {0.f, 0.f, 0.f, 0.f};
  const bool lact = (t < 75);

  for (int i = 0; i < deg; ++i) {
    const int pidx = base + i;
    const int s = srcs[pidx];
    const float wgt = af[pidx];
    const float wl = afl[pidx];

    float4 sv = ld4b(S + (size_t)pidx * 1024 + c0);
    float4 p1 = ld4b(P + (size_t)s * 2048 + c0);
    float4 nf4 = ld4b(nf_bf + (size_t)s * 1024 + c0);
    const float p1a[4] = {p1.x, p1.y, p1.z, p1.w};
    const float sva[4] = {sv.x, sv.y, sv.z, sv.w};
    const float nfa[4] = {nf4.x, nf4.y, nf4.z, nf4.w};
#pragma unroll
    for (int j = 0; j < 4; ++j) {
      float ef = fmaxf(p1a[j] + p2[j] + sva[j], 0.f);
      acc[j] = fmaf(wgt, nfa[j] + ef, acc[j]);
    }
    if (lact) {
      float4 wv = ld4b(w2v_pad + (size_t)s * 320 + c0);
      accl[0] = fmaf(wl, wv.x, accl[0]);
      accl[1] = fmaf(wl, wv.y, accl[1]);
      accl[2] = fmaf(wl, wv.z, accl[2]);
      accl[3] = fmaf(wl, wv.w, accl[3]);
    }
  }
  st4b(zf + (size_t)node * 1024 + c0, acc[0], acc[1], acc[2], acc[3]);
  if (lact)
    st4b(zfl_pad + (size_t)node * 320 + c0, accl[0], accl[1], accl[2], accl[3]);
  else if (t < 80)
    st4b(zfl_pad + (size_t)node * 320 + c0, 0.f, 0.f, 0.f, 0.f);
}

//---------------------------------------------------------------------
// node_z v9 (FALLBACK when workspace too small for S)
//---------------------------------------------------------------------
__global__ __launch_bounds__(256)
void gnn9_node_z(const int* __restrict__ off, const int* __restrict__ elist,
                 const int* __restrict__ src, const float* __restrict__ af,
                 const float* __restrict__ afl, const bf16* __restrict__ nf_bf,
                 const bf16* __restrict__ w2v_pad, const float* __restrict__ s_f,
                 const float* __restrict__ We, const float* __restrict__ be,
                 const bf16* __restrict__ P, bf16* __restrict__ zf,
                 bf16* __restrict__ zfl_pad)
{
  const int node = blockIdx.x;
  const int t = threadIdx.x;
  const int c0 = 4 * t;
  const int base = off[node];
  const int deg = off[node + 1] - base;

  float wef[16][4];
#pragma unroll
  for (int k = 0; k < 16; ++k) {
    float4 v = *(const float4*)(We + (size_t)(1024 + k) * 1024 + c0);
    wef[k][0] = v.x; wef[k][1] = v.y; wef[k][2] = v.z; wef[k][3] = v.w;
  }
  float4 p2v = ld4b(P + (size_t)node * 2048 + 1024 + c0);
  float4 bev = *(const float4*)(be + c0);
  const float p2[4] = {p2v.x + bev.x, p2v.y + bev.y, p2v.z + bev.z, p2v.w + bev.w};

  float acc[4] = {0.f, 0.f, 0.f, 0.f};
  float accl[4] = {0.f, 0.f, 0.f, 0.f};
  const bool lact = (t < 75);

  for (int i = 0; i < deg; ++i) {
    const int e = elist[base + i];
    const int s = src[e];
    const float wgt = af[e];
    const float wl = afl[e];

    float sfv[16];
    {
      const float4* sp = (const float4*)(s_f + (size_t)e * 16);
      float4 s0 = sp[0], s1 = sp[1], s2 = sp[2], s3 = sp[3];
      sfv[0] = s0.x; sfv[1] = s0.y; sfv[2] = s0.z; sfv[3] = s0.w;
      sfv[4] = s1.x; sfv[5] = s1.y; sfv[6] = s1.z; sfv[7] = s1.w;
      sfv[8] = s2.x; sfv[9] = s2.y; sfv[10] = s2.z; sfv[11] = s2.w;
      sfv[12] = s3.x; sfv[13] = s3.y; sfv[14] = s3.z; sfv[15] = s3.w;
    }

    float4 p1 = ld4b(P + (size_t)s * 2048 + c0);
    float4 nf4 = ld4b(nf_bf + (size_t)s * 1024 + c0);
    const float p1a[4] = {p1.x, p1.y, p1.z, p1.w};
    const float nfa[4] = {nf4.x, nf4.y, nf4.z, nf4.w};
#pragma unroll
    for (int j = 0; j < 4; ++j) {
      float ef = p1a[j] + p2[j];
#pragma unroll
      for (int k = 0; k < 16; ++k) ef = fmaf(sfv[k], wef[k][j], ef);
      ef = fmaxf(ef, 0.f);
      acc[j] = fmaf(wgt, nfa[j] + ef, acc[j]);
    }
    if (lact) {
      float4 wv = ld4b(w2v_pad + (size_t)s * 320 + c0);
      accl[0] = fmaf(wl, wv.x, accl[0]);
      accl[1] = fmaf(wl, wv.y, accl[1]);
      accl[2] = fmaf(wl, wv.z, accl[2]);
      accl[3] = fmaf(wl, wv.w, accl[3]);
    }
  }
  st4b(zf + (size_t)node * 1024 + c0, acc[0], acc[1], acc[2], acc[3]);
  if (lact)
    st4b(zfl_pad + (size_t)node * 320 + c0, accl[0], accl[1], accl[2], accl[3]);
  else if (t < 80)
    st4b(zfl_pad + (size_t)node * 320 + c0, 0.f, 0.f, 0.f, 0.f);
}

//=====================================================================
extern "C" void kernel_launch(void* const* d_in, const int* in_sizes, int n_in,
                              void* d_out, int out_size, void* d_ws, size_t ws_size,
                              hipStream_t stream)
{
  (void)hipGetLastError();
  if (n_in != 17) { (void)hipMemsetAsync(d_out, 0x41, 4096, stream); return; }

  const float* n_f = (const float*)d_in[0];
  const float* w2v = (const float*)d_in[1];
  const float* s_f = (const float*)d_in[2];
  const int*   src = (const int*)d_in[3];
  const int*   dst = (const int*)d_in[4];
  const float* We  = (const float*)d_in[5];
  const float* be  = (const float*)d_in[6];
  const float* Wel = (const float*)d_in[7];
  const float* bel = (const float*)d_in[8];
  const float* Wa  = (const float*)d_in[9];
  const float* ba  = (const float*)d_in[10];
  const float* Wal = (const float*)d_in[11];
  const float* bal = (const float*)d_in[12];
  const float* Wn  = (const float*)d_in[13];
  const float* bn  = (const float*)d_in[14];
  const float* Wnl = (const float*)d_in[15];
  const float* bnl = (const float*)d_in[16];
  float* out  = (float*)d_out;
  float* out2 = out + OUT0_ELEMS;

  char* ws = (char*)d_ws;
  size_t o = 0;
  auto alloc = [&](size_t bytes) -> void* {
    void* p = ws + o; o += bytes; o = (o + 255) & ~(size_t)255; return p;
  };
  bf16* P        = (bf16*)alloc((size_t)N_NODES * 2048 * 2);
  bf16* Q        = (bf16*)alloc((size_t)N_NODES * 1280 * 2);
  bf16* zf       = (bf16*)alloc((size_t)N_NODES * 1024 * 2);
  bf16* zfl_pad  = (bf16*)alloc((size_t)N_NODES * 320 * 2);
  bf16* nf_bf    = (bf16*)alloc((size_t)N_NODES * 1024 * 2);
  bf16* w2v_pad  = (bf16*)alloc((size_t)N_NODES * 320 * 2);
  bf16* WeT      = (bf16*)alloc((size_t)2048 * 1024 * 2);
  bf16* WnT      = (bf16*)alloc((size_t)1024 * 2048 * 2);
  bf16* WelT     = (bf16*)alloc((size_t)1280 * 320 * 2);
  bf16* WnlT     = (bf16*)alloc((size_t)384 * 640 * 2);
  float* af      = (float*)alloc((size_t)N_EDGES * 4);
  float* afl     = (float*)alloc((size_t)N_EDGES * 4);
  int* cnt       = (int*)alloc((size_t)N_NODES * 4);
  int* offs      = (int*)alloc((size_t)(N_NODES + 1) * 4);
  int* cur       = (int*)alloc((size_t)N_NODES * 4);
  int* elist     = (int*)alloc((size_t)N_EDGES * 4);
  size_t base_end = o;
  if (base_end > ws_size) { (void)hipMemsetAsync(d_out, 0x42, 4096, stream); return; }

  // Extended (CSR-sorted S path) allocations — used only if ws fits.
  bf16* sfp     = (bf16*)alloc((size_t)N_EDGES * 32 * 2);
  bf16* WeTtail = (bf16*)alloc((size_t)1024 * 32 * 2);
  bf16* S       = (bf16*)alloc((size_t)N_EDGES * 1024 * 2);
  int* srcs     = (int*)alloc((size_t)N_EDGES * 4);
  int* dsts     = (int*)alloc((size_t)N_EDGES * 4);
  const bool useS = (o <= ws_size);

  gnn6_zero<<<N_NODES / 256, 256, 0, stream>>>(cnt, N_NODES);
  gnn7_cvt<<<(N_NODES * 1024 / 8 + 255) / 256, 256, 0, stream>>>(n_f, nf_bf,
                                                                 N_NODES * 1024 / 8);
  gnn8_pad_w2v<<<(N_NODES * 80 + 255) / 256, 256, 0, stream>>>(w2v, w2v_pad);
  { dim3 g(32, 64); gnn10_t_We<<<g, 256, 0, stream>>>(We, WeT); }
  { dim3 g(64, 32); gnn10_t_Wn<<<g, 256, 0, stream>>>(Wn, WnT); }
  { dim3 g(10, 40); gnn10_t_Wel<<<g, 256, 0, stream>>>(Wel, WelT); }
  { dim3 g(20, 12); gnn10_t_Wnl<<<g, 256, 0, stream>>>(Wnl, WnlT); }

  // CSR build first (needed by the sorted scoring path).
  gnn6_count<<<N_EDGES / 256, 256, 0, stream>>>(dst, cnt);
  gnn6_scan<<<1, 1024, 0, stream>>>(cnt, offs, cur);
  if (useS) {
    gnn14_fill<<<N_EDGES / 256, 256, 0, stream>>>(dst, src, cur, elist, srcs, dsts);
    gnn12_t_Wetail<<<4, 256, 0, stream>>>(We, WeTtail);
    gnn14_sfp<<<N_EDGES / 256, 256, 0, stream>>>(s_f, elist, sfp);
  } else {
    gnn6_fill<<<N_EDGES / 256, 256, 0, stream>>>(dst, cur, elist);
  }

  {
    dim3 g(2048 / 128, N_NODES / 128);
    gnn17_mm_P<<<g, 256, 0, stream>>>(nf_bf, WeT, P, useS ? be : nullptr);
  }
  {
    dim3 g(1280 / 128, N_NODES / 128);
    gnn10_mm_Q<<<g, 256, 0, stream>>>(w2v_pad, WelT, Q, useS ? bel : nullptr);
  }

  if (useS) {
    gnn18_score<<<N_EDGES / 16, 256, 0, stream>>>(
        sfp, WeTtail, srcs, dsts, Wa, ba, Wal, bal, P, Q, S, af, afl);
    gnn14_alpha<<<N_NODES / 256, 256, 0, stream>>>(offs, af, afl);
    gnn14_node_z<<<N_NODES, 256, 0, stream>>>(offs, srcs, af, afl, nf_bf,
                                              w2v_pad, S, P, zf, zfl_pad);
  } else {
    gnn11_edge_score<<<N_EDGES / 8, 256, 0, stream>>>(src, dst, s_f, We, be, Wa,
                                                      ba, bel, Wal, bal, P, Q,
                                                      af, afl);
    gnn6_alpha<<<N_NODES / 256, 256, 0, stream>>>(offs, elist, af, afl);
    gnn9_node_z<<<N_NODES, 256, 0, stream>>>(offs, elist, src, af, afl, nf_bf,
                                             w2v_pad, s_f, We, be, P, zf, zfl_pad);
  }

  {
    dim3 g(1024 / 128, N_NODES / 128);
    gnn17_mm_out_n<<<g, 256, 0, stream>>>(nf_bf, zf, WnT, bn, out);
  }
  {
    dim3 g(384 / 128, N_NODES / 128);
    gnn10_mm_out_l<<<g, 256, 0, stream>>>(w2v_pad, zfl_pad, WnlT, bnl, out2);
  }

  if (hipGetLastError() != hipSuccess) (void)hipMemsetAsync(d_out, 0x44, 4096, stream);
}

// Round 11
// 475.852 us; speedup vs baseline: 1.0497x; 1.0497x over previous
//
#include <hip/hip_runtime.h>
#include <hip/hip_bf16.h>

#define N_NODES 8192
#define N_EDGES 65536
#define OUT0_ELEMS ((size_t)N_NODES * 1024)

using bf16 = __hip_bfloat16;
typedef __attribute__((ext_vector_type(8))) short short8;
typedef __attribute__((ext_vector_type(4))) float f32x4;

__device__ __forceinline__ float b2f(bf16 x) { return __bfloat162float(x); }
__device__ __forceinline__ bf16 f2b(float x) { return __float2bfloat16(x); }
__device__ __forceinline__ unsigned short bbits(float x)
{
  union { bf16 h; unsigned short u; } v; v.h = f2b(x); return v.u;
}
__device__ __forceinline__ unsigned pack2(float a, float b)
{
  return (unsigned)bbits(a) | ((unsigned)bbits(b) << 16);
}
__device__ __forceinline__ float4 cvt2x(uint2 u)
{
  float4 r;
  r.x = __uint_as_float(u.x << 16);
  r.y = __uint_as_float(u.x & 0xffff0000u);
  r.z = __uint_as_float(u.y << 16);
  r.w = __uint_as_float(u.y & 0xffff0000u);
  return r;
}
__device__ __forceinline__ float4 ld4b(const bf16* p)
{
  uint2 u = *(const uint2*)p;
  return cvt2x(u);
}
__device__ __forceinline__ void st4b(bf16* p, float a, float b, float c, float d)
{
  uint2 v; v.x = pack2(a, b); v.y = pack2(c, d);
  *(uint2*)p = v;
}

// Async global->LDS, 16B per lane: LDS dest = base + lane*16 (wave-uniform
// base), global src per-lane. Requires linear LDS tiles (guide m97/m104).
__device__ __forceinline__ void gll16(const bf16* g, short* l)
{
  __builtin_amdgcn_global_load_lds(
      (const __attribute__((address_space(1))) void*)g,
      (__attribute__((address_space(3))) void*)l, 16, 0, 0);
}

// Kept so any harness-side reference to the stub symbol still resolves.
__global__ void GNN_27650999451833_kernel() {}

__global__ void gnn6_zero(int* __restrict__ p, int n)
{
  int i = blockIdx.x * blockDim.x + threadIdx.x;
  if (i < n) p[i] = 0;
}

//---------------------------------------------------------------------
// f32 -> bf16 bulk convert (8 elems/thread)
//---------------------------------------------------------------------
__global__ __launch_bounds__(256)
void gnn7_cvt(const float* __restrict__ src, bf16* __restrict__ dst, int n8)
{
  int i = blockIdx.x * blockDim.x + threadIdx.x;
  if (i < n8) {
    float4 a = ((const float4*)src)[2 * i];
    float4 b = ((const float4*)src)[2 * i + 1];
    uint4 p;
    p.x = pack2(a.x, a.y); p.y = pack2(a.z, a.w);
    p.z = pack2(b.x, b.y); p.w = pack2(b.z, b.w);
    ((uint4*)dst)[i] = p;
  }
}

//---------------------------------------------------------------------
// w2v[8192,300](f32) -> w2v_pad[8192,320](bf16, cols>=300 zero)
//---------------------------------------------------------------------
__global__ __launch_bounds__(256)
void gnn8_pad_w2v(const float* __restrict__ src, bf16* __restrict__ dst)
{
  int idx = blockIdx.x * blockDim.x + threadIdx.x;
  if (idx >= N_NODES * 80) return;
  int r = idx / 80, c0 = (idx % 80) * 4;
  float v[4];
#pragma unroll
  for (int j = 0; j < 4; ++j) {
    int c = c0 + j;
    v[j] = (c < 300) ? src[(size_t)r * 300 + c] : 0.f;
  }
  uint2 p; p.x = pack2(v[0], v[1]); p.y = pack2(v[2], v[3]);
  *(uint2*)(dst + (size_t)r * 320 + c0) = p;
}

//---------------------------------------------------------------------
// WeTtail[1024][32](bf16): row c, k<16 = We[1024+k][c], else 0
//---------------------------------------------------------------------
__global__ __launch_bounds__(256)
void gnn12_t_Wetail(const float* __restrict__ We, bf16* __restrict__ BT)
{
  int c = blockIdx.x * 256 + threadIdx.x;
  if (c >= 1024) return;
  bf16* row = BT + (size_t)c * 32;
#pragma unroll
  for (int k = 0; k < 16; ++k)
    row[k] = f2b(We[(size_t)(1024 + k) * 1024 + c]);
#pragma unroll
  for (int k = 16; k < 32; ++k) row[k] = f2b(0.f);
}

//---------------------------------------------------------------------
// Transposed weight prepacks (LDS 32x32 tile transpose, 256 thr = 32x8)
//---------------------------------------------------------------------
// WeT[2048][1024] <- We_eff[k][n] = n<1024 ? We[k][n] : We[1040+k][n-1024]
__global__ __launch_bounds__(256)
void gnn10_t_We(const float* __restrict__ src, bf16* __restrict__ dst)
{
  __shared__ float tile[32][33];
  const int kb = blockIdx.x * 32, nb = blockIdx.y * 32;
  const int tx = threadIdx.x & 31, ty = threadIdx.x >> 5;
  const int n = nb + tx;
#pragma unroll
  for (int i = ty; i < 32; i += 8)
    tile[i][tx] = (n < 1024)
        ? src[(size_t)(kb + i) * 1024 + n]
        : src[(size_t)(1040 + kb + i) * 1024 + (n - 1024)];
  __syncthreads();
#pragma unroll
  for (int i = ty; i < 32; i += 8)
    dst[(size_t)(nb + i) * 1024 + kb + tx] = f2b(tile[tx][i]);
}

// WnT[1024][2048] <- Wn[k][n], k<2048, n<1024
__global__ __launch_bounds__(256)
void gnn10_t_Wn(const float* __restrict__ src, bf16* __restrict__ dst)
{
  __shared__ float tile[32][33];
  const int kb = blockIdx.x * 32, nb = blockIdx.y * 32;
  const int tx = threadIdx.x & 31, ty = threadIdx.x >> 5;
#pragma unroll
  for (int i = ty; i < 32; i += 8)
    tile[i][tx] = src[(size_t)(kb + i) * 1024 + nb + tx];
  __syncthreads();
#pragma unroll
  for (int i = ty; i < 32; i += 8)
    dst[(size_t)(nb + i) * 2048 + kb + tx] = f2b(tile[tx][i]);
}

// WelT_pad[1280][320] <- k<300 ? (n<600?Wel[k][n] : n<1200?Wel[300+k][n-600]:0):0
__global__ __launch_bounds__(256)
void gnn10_t_Wel(const float* __restrict__ src, bf16* __restrict__ dst)
{
  __shared__ float tile[32][33];
  const int kb = blockIdx.x * 32, nb = blockIdx.y * 32;
  const int tx = threadIdx.x & 31, ty = threadIdx.x >> 5;
  const int n = nb + tx;
#pragma unroll
  for (int i = ty; i < 32; i += 8) {
    int k = kb + i;
    float v = 0.f;
    if (k < 300) {
      if (n < 600)       v = src[(size_t)k * 600 + n];
      else if (n < 1200) v = src[(size_t)(300 + k) * 600 + (n - 600)];
    }
    tile[i][tx] = v;
  }
  __syncthreads();
#pragma unroll
  for (int i = ty; i < 32; i += 8)
    dst[(size_t)(nb + i) * 320 + kb + tx] = f2b(tile[tx][i]);
}

// WnlT_pad[384][640] <- kr(k)=k<300?k : 320<=k<620?k-20 : -1 ; n<300
__global__ __launch_bounds__(256)
void gnn10_t_Wnl(const float* __restrict__ src, bf16* __restrict__ dst)
{
  __shared__ float tile[32][33];
  const int kb = blockIdx.x * 32, nb = blockIdx.y * 32;
  const int tx = threadIdx.x & 31, ty = threadIdx.x >> 5;
  const int n = nb + tx;
#pragma unroll
  for (int i = ty; i < 32; i += 8) {
    int k = kb + i;
    int kr = (k < 300) ? k : ((k >= 320 && k < 620) ? (k - 20) : -1);
    tile[i][tx] = (kr >= 0 && n < 300) ? src[(size_t)kr * 300 + n] : 0.f;
  }
  __syncthreads();
#pragma unroll
  for (int i = ty; i < 32; i += 8)
    dst[(size_t)(nb + i) * 640 + kb + tx] = f2b(tile[tx][i]);
}

//---------------------------------------------------------------------
// MFMA GEMM v17: global_load_lds-staged. Linear LDS [128][32]/operand.
//---------------------------------------------------------------------
// P[8192,2048] = nf_bf[8192,1024] @ WeT^T ; if be: fold be into cols>=1024
__global__ __launch_bounds__(256)
void gnn17_mm_P(const bf16* __restrict__ A, const bf16* __restrict__ BT,
                bf16* __restrict__ P, const float* __restrict__ be)
{
  __shared__ short As[128 * 32];
  __shared__ short Bs[128 * 32];
  const int t = threadIdx.x;
  const int col0 = blockIdx.x * 128, row0 = blockIdx.y * 128;
  const int lane = t & 63, w = t >> 6, m16 = lane & 15, q = lane >> 4;
  const int wr = w >> 1, wc = w & 1;

  f32x4 acc[4][4];
#pragma unroll
  for (int mi = 0; mi < 4; ++mi)
#pragma unroll
    for (int ni = 0; ni < 4; ++ni) acc[mi][ni] = (f32x4){0.f, 0.f, 0.f, 0.f};

  const int glr = w * 16 + (lane >> 2);
  const int glc = (lane & 3) * 8;
  short* lA0 = &As[w * 512];
  short* lA1 = &As[2048 + w * 512];
  short* lB0 = &Bs[w * 512];
  short* lB1 = &Bs[2048 + w * 512];
  const bf16* ar0 = A + (size_t)(row0 + glr) * 1024 + glc;
  const bf16* ar1 = A + (size_t)(row0 + 64 + glr) * 1024 + glc;
  const bf16* br0 = BT + (size_t)(col0 + glr) * 1024 + glc;
  const bf16* br1 = BT + (size_t)(col0 + 64 + glr) * 1024 + glc;

  for (int k0 = 0; k0 < 1024; k0 += 32) {
    if (k0) __syncthreads();
    gll16(ar0 + k0, lA0);
    gll16(ar1 + k0, lA1);
    gll16(br0 + k0, lB0);
    gll16(br1 + k0, lB1);
    __syncthreads();
    short8 af[4];
#pragma unroll
    for (int mi = 0; mi < 4; ++mi)
      af[mi] = *(const short8*)&As[(wr * 64 + mi * 16 + m16) * 32 + 8 * q];
#pragma unroll
    for (int ni = 0; ni < 4; ++ni) {
      short8 bfv = *(const short8*)&Bs[(wc * 64 + ni * 16 + m16) * 32 + 8 * q];
#pragma unroll
      for (int mi = 0; mi < 4; ++mi)
        acc[mi][ni] =
            __builtin_amdgcn_mfma_f32_16x16x32_bf16(af[mi], bfv, acc[mi][ni], 0, 0, 0);
    }
  }
#pragma unroll
  for (int mi = 0; mi < 4; ++mi)
#pragma unroll
    for (int ni = 0; ni < 4; ++ni) {
      int c = col0 + wc * 64 + ni * 16 + m16;
      float bias = (be != nullptr && c >= 1024) ? be[c - 1024] : 0.f;
#pragma unroll
      for (int r = 0; r < 4; ++r)
        P[(size_t)(row0 + wr * 64 + mi * 16 + 4 * q + r) * 2048 + c] =
            f2b(acc[mi][ni][r] + bias);
    }
}

// out0[8192,1024](f32) = relu([nf_bf | zf] @ WnT^T + bn), K=2048
__global__ __launch_bounds__(256)
void gnn17_mm_out_n(const bf16* __restrict__ A0, const bf16* __restrict__ A1,
                    const bf16* __restrict__ BT, const float* __restrict__ bn,
                    float* __restrict__ out)
{
  __shared__ short As[128 * 32];
  __shared__ short Bs[128 * 32];
  const int t = threadIdx.x;
  const int col0 = blockIdx.x * 128, row0 = blockIdx.y * 128;
  const int lane = t & 63, w = t >> 6, m16 = lane & 15, q = lane >> 4;
  const int wr = w >> 1, wc = w & 1;

  f32x4 acc[4][4];
#pragma unroll
  for (int mi = 0; mi < 4; ++mi)
#pragma unroll
    for (int ni = 0; ni < 4; ++ni) acc[mi][ni] = (f32x4){0.f, 0.f, 0.f, 0.f};

  const int glr = w * 16 + (lane >> 2);
  const int glc = (lane & 3) * 8;
  short* lA0 = &As[w * 512];
  short* lA1 = &As[2048 + w * 512];
  short* lB0 = &Bs[w * 512];
  short* lB1 = &Bs[2048 + w * 512];
  const bf16* br0 = BT + (size_t)(col0 + glr) * 2048 + glc;
  const bf16* br1 = BT + (size_t)(col0 + 64 + glr) * 2048 + glc;

  for (int k0 = 0; k0 < 2048; k0 += 32) {
    if (k0) __syncthreads();
    const bf16* ab = (k0 < 1024) ? A0 : A1;
    const int kk = (k0 < 1024) ? k0 : (k0 - 1024);
    gll16(ab + (size_t)(row0 + glr) * 1024 + kk + glc, lA0);
    gll16(ab + (size_t)(row0 + 64 + glr) * 1024 + kk + glc, lA1);
    gll16(br0 + k0, lB0);
    gll16(br1 + k0, lB1);
    __syncthreads();
    short8 af[4];
#pragma unroll
    for (int mi = 0; mi < 4; ++mi)
      af[mi] = *(const short8*)&As[(wr * 64 + mi * 16 + m16) * 32 + 8 * q];
#pragma unroll
    for (int ni = 0; ni < 4; ++ni) {
      short8 bfv = *(const short8*)&Bs[(wc * 64 + ni * 16 + m16) * 32 + 8 * q];
#pragma unroll
      for (int mi = 0; mi < 4; ++mi)
        acc[mi][ni] =
            __builtin_amdgcn_mfma_f32_16x16x32_bf16(af[mi], bfv, acc[mi][ni], 0, 0, 0);
    }
  }
#pragma unroll
  for (int mi = 0; mi < 4; ++mi)
#pragma unroll
    for (int ni = 0; ni < 4; ++ni) {
      int c = col0 + wc * 64 + ni * 16 + m16;
      float bias = bn[c];
#pragma unroll
      for (int r = 0; r < 4; ++r) {
        float v = acc[mi][ni][r] + bias;
        out[(size_t)(row0 + wr * 64 + mi * 16 + 4 * q + r) * 1024 + c] =
            fmaxf(v, 0.f);
      }
    }
}

// Q[8192,1280](bf16) = w2v_pad[8192,320] @ WelT^T, K=320
// if bel: fold bel into cols [600,1200)
__global__ __launch_bounds__(256)
void gnn10_mm_Q(const bf16* __restrict__ A, const bf16* __restrict__ BT,
                bf16* __restrict__ Q, const float* __restrict__ bel)
{
  __shared__ short As[128 * 40];
  __shared__ short Bs[128 * 40];
  const int t = threadIdx.x;
  const int col0 = blockIdx.x * 128, row0 = blockIdx.y * 128;
  const int lane = t & 63, w = t >> 6, m16 = lane & 15, q = lane >> 4;
  const int wr = w >> 1, wc = w & 1;

  f32x4 acc[4][4];
#pragma unroll
  for (int mi = 0; mi < 4; ++mi)
#pragma unroll
    for (int ni = 0; ni < 4; ++ni) acc[mi][ni] = (f32x4){0.f, 0.f, 0.f, 0.f};

  const int ar = t >> 1, ah = (t & 1) * 16;
  const bf16* aptr = A + (size_t)(row0 + ar) * 320 + ah;
  const bf16* bptr = BT + (size_t)(col0 + ar) * 320 + ah;

  uint4 a0 = *(const uint4*)(aptr);
  uint4 a1 = *(const uint4*)(aptr + 8);
  uint4 b0 = *(const uint4*)(bptr);
  uint4 b1 = *(const uint4*)(bptr + 8);

  for (int k0 = 0; k0 < 320; k0 += 32) {
    if (k0) __syncthreads();
    *(uint4*)&As[ar * 40 + ah] = a0;
    *(uint4*)&As[ar * 40 + ah + 8] = a1;
    *(uint4*)&Bs[ar * 40 + ah] = b0;
    *(uint4*)&Bs[ar * 40 + ah + 8] = b1;
    __syncthreads();
    if (k0 + 32 < 320) {
      a0 = *(const uint4*)(aptr + k0 + 32);
      a1 = *(const uint4*)(aptr + k0 + 40);
      b0 = *(const uint4*)(bptr + k0 + 32);
      b1 = *(const uint4*)(bptr + k0 + 40);
    }
    short8 af[4];
#pragma unroll
    for (int mi = 0; mi < 4; ++mi)
      af[mi] = *(const short8*)&As[(wr * 64 + mi * 16 + m16) * 40 + 8 * q];
#pragma unroll
    for (int ni = 0; ni < 4; ++ni) {
      short8 bfv = *(const short8*)&Bs[(wc * 64 + ni * 16 + m16) * 40 + 8 * q];
#pragma unroll
      for (int mi = 0; mi < 4; ++mi)
        acc[mi][ni] =
            __builtin_amdgcn_mfma_f32_16x16x32_bf16(af[mi], bfv, acc[mi][ni], 0, 0, 0);
    }
  }
#pragma unroll
  for (int mi = 0; mi < 4; ++mi)
#pragma unroll
    for (int ni = 0; ni < 4; ++ni) {
      int c = col0 + wc * 64 + ni * 16 + m16;
      float bias = (bel != nullptr && c >= 600 && c < 1200) ? bel[c - 600] : 0.f;
#pragma unroll
      for (int r = 0; r < 4; ++r)
        Q[(size_t)(row0 + wr * 64 + mi * 16 + 4 * q + r) * 1280 + c] =
            f2b(acc[mi][ni][r] + bias);
    }
}

// out1[8192,300](f32) = relu([w2v_pad | zfl_pad] @ WnlT^T + bnl), K=640
__global__ __launch_bounds__(256)
void gnn10_mm_out_l(const bf16* __restrict__ A0, const bf16* __restrict__ A1,
                    const bf16* __restrict__ BT, const float* __restrict__ bnl,
                    float* __restrict__ out2)
{
  __shared__ short As[128 * 40];
  __shared__ short Bs[128 * 40];
  const int t = threadIdx.x;
  const int col0 = blockIdx.x * 128, row0 = blockIdx.y * 128;
  const int lane = t & 63, w = t >> 6, m16 = lane & 15, q = lane >> 4;
  const int wr = w >> 1, wc = w & 1;

  f32x4 acc[4][4];
#pragma unroll
  for (int mi = 0; mi < 4; ++mi)
#pragma unroll
    for (int ni = 0; ni < 4; ++ni) acc[mi][ni] = (f32x4){0.f, 0.f, 0.f, 0.f};

  const int ar = t >> 1, ah = (t & 1) * 16;
  const bf16* ap0 = A0 + (size_t)(row0 + ar) * 320 + ah;
  const bf16* ap1 = A1 + (size_t)(row0 + ar) * 320 + ah;
  const bf16* bptr = BT + (size_t)(col0 + ar) * 640 + ah;

  uint4 a0 = *(const uint4*)(ap0);
  uint4 a1 = *(const uint4*)(ap0 + 8);
  uint4 b0 = *(const uint4*)(bptr);
  uint4 b1 = *(const uint4*)(bptr + 8);

  for (int k0 = 0; k0 < 640; k0 += 32) {
    if (k0) __syncthreads();
    *(uint4*)&As[ar * 40 + ah] = a0;
    *(uint4*)&As[ar * 40 + ah + 8] = a1;
    *(uint4*)&Bs[ar * 40 + ah] = b0;
    *(uint4*)&Bs[ar * 40 + ah + 8] = b1;
    __syncthreads();
    if (k0 + 32 < 640) {
      int kn = k0 + 32;
      const bf16* ap = (kn < 320) ? (ap0 + kn) : (ap1 + (kn - 320));
      a0 = *(const uint4*)(ap);
      a1 = *(const uint4*)(ap + 8);
      b0 = *(const uint4*)(bptr + kn);
      b1 = *(const uint4*)(bptr + kn + 8);
    }
    short8 af[4];
#pragma unroll
    for (int mi = 0; mi < 4; ++mi)
      af[mi] = *(const short8*)&As[(wr * 64 + mi * 16 + m16) * 40 + 8 * q];
#pragma unroll
    for (int ni = 0; ni < 4; ++ni) {
      short8 bfv = *(const short8*)&Bs[(wc * 64 + ni * 16 + m16) * 40 + 8 * q];
#pragma unroll
      for (int mi = 0; mi < 4; ++mi)
        acc[mi][ni] =
            __builtin_amdgcn_mfma_f32_16x16x32_bf16(af[mi], bfv, acc[mi][ni], 0, 0, 0);
    }
  }
#pragma unroll
  for (int mi = 0; mi < 4; ++mi)
#pragma unroll
    for (int ni = 0; ni < 4; ++ni) {
      int c = col0 + wc * 64 + ni * 16 + m16;
      if (c < 300) {
        float bias = bnl[c];
#pragma unroll
        for (int r = 0; r < 4; ++r) {
          float v = acc[mi][ni][r] + bias;
          out2[(size_t)(row0 + wr * 64 + mi * 16 + 4 * q + r) * 300 + c] =
              fmaxf(v, 0.f);
        }
      }
    }
}

//---------------------------------------------------------------------
// CSR build (v14: fill also emits srcs/dsts in CSR order)
//---------------------------------------------------------------------
__global__ void gnn6_count(const int* __restrict__ dst, int* __restrict__ cnt)
{
  int e = blockIdx.x * blockDim.x + threadIdx.x;
  if (e < N_EDGES) atomicAdd(&cnt[dst[e]], 1);
}

__global__ __launch_bounds__(1024)
void gnn6_scan(const int* __restrict__ cnt, int* __restrict__ off, int* __restrict__ cur)
{
  __shared__ int sh[1024];
  const int t = threadIdx.x;
  int local[8]; int sum = 0;
#pragma unroll
  for (int i = 0; i < 8; ++i) { int v = cnt[t * 8 + i]; local[i] = sum; sum += v; }
  sh[t] = sum;
  __syncthreads();
  for (int d = 1; d < 1024; d <<= 1) {
    int v = (t >= d) ? sh[t - d] : 0;
    __syncthreads();
    sh[t] += v;
    __syncthreads();
  }
  int basev = (t > 0) ? sh[t - 1] : 0;
#pragma unroll
  for (int i = 0; i < 8; ++i) { int o = basev + local[i]; off[t * 8 + i] = o; cur[t * 8 + i] = o; }
  if (t == 1023) off[8192] = sh[1023];
}

__global__ void gnn6_fill(const int* __restrict__ dst, int* __restrict__ cur,
                          int* __restrict__ elist)
{
  int e = blockIdx.x * blockDim.x + threadIdx.x;
  if (e < N_EDGES) { int p = atomicAdd(&cur[dst[e]], 1); elist[p] = e; }
}

__global__ void gnn14_fill(const int* __restrict__ dst, const int* __restrict__ src,
                           int* __restrict__ cur, int* __restrict__ elist,
                           int* __restrict__ srcs, int* __restrict__ dsts)
{
  int e = blockIdx.x * blockDim.x + threadIdx.x;
  if (e < N_EDGES) {
    int d = dst[e];
    int p = atomicAdd(&cur[d], 1);
    elist[p] = e;
    srcs[p] = src[e];
    dsts[p] = d;
  }
}

// sfp[p][32](bf16) = padded s_f[elist[p]] — CSR-ordered edge features.
__global__ __launch_bounds__(256)
void gnn14_sfp(const float* __restrict__ s_f, const int* __restrict__ elist,
               bf16* __restrict__ sfp)
{
  int p = blockIdx.x * 256 + threadIdx.x;
  if (p >= N_EDGES) return;
  int e = elist[p];
  const float4* sp = (const float4*)(s_f + (size_t)e * 16);
  float4 s0 = sp[0], s1 = sp[1], s2 = sp[2], s3 = sp[3];
  uint4 lo, hi;
  lo.x = pack2(s0.x, s0.y); lo.y = pack2(s0.z, s0.w);
  lo.z = pack2(s1.x, s1.y); lo.w = pack2(s1.z, s1.w);
  hi.x = pack2(s2.x, s2.y); hi.y = pack2(s2.z, s2.w);
  hi.z = pack2(s3.x, s3.y); hi.w = pack2(s3.z, s3.w);
  uint4* dp = (uint4*)(sfp + (size_t)p * 32);
  dp[0] = lo; dp[1] = hi;
  dp[2] = (uint4){0, 0, 0, 0}; dp[3] = (uint4){0, 0, 0, 0};
}

//---------------------------------------------------------------------
// FUSED v14 (CSR-ordered, measured best 83.2us): S tile for positions
// [p0,p0+16) via MFMA into LDS (+ coalesced HBM write for node_z),
// then edge scores with dst-sorted gathers (2 batches of 8).
// NOTE: perturbation neighborhood explored and worse — 8-edge tile
// (R8: WeTtail re-read doubles), single-pass 16 (R10: VGPR 76, occ
// 30%), no-S-write + recompute in node_z (R7: serializes node_z).
//---------------------------------------------------------------------
#define SLD_STRIDE 1032
__global__ __launch_bounds__(256)
void gnn14_mm_S_score(const bf16* __restrict__ sfp, const bf16* __restrict__ WeTtail,
                      const int* __restrict__ srcs, const int* __restrict__ dsts,
                      const float* __restrict__ Wa, const float* __restrict__ ba,
                      const float* __restrict__ Wal, const float* __restrict__ bal,
                      const bf16* __restrict__ P, const bf16* __restrict__ Q,
                      bf16* __restrict__ S, float* __restrict__ af,
                      float* __restrict__ afl)
{
  __shared__ short Sld[16 * SLD_STRIDE];
  __shared__ float shf[8][4], shl[8][4];
  const int t = threadIdx.x;
  const int lane = t & 63, w = t >> 6, m16 = lane & 15, q = lane >> 4;
  const int p0 = blockIdx.x * 16;

  // ---- phase 1: S rows = sfp @ WeTtail^T (K=32), operand-swapped ----
  short8 bfr = *(const short8*)(sfp + (size_t)(p0 + m16) * 32 + 8 * q);
  const int cb = w * 256;
#pragma unroll
  for (int ni = 0; ni < 16; ++ni) {
    short8 afr = *(const short8*)(WeTtail + (size_t)(cb + ni * 16 + m16) * 32 + 8 * q);
    f32x4 acc = __builtin_amdgcn_mfma_f32_16x16x32_bf16(
        afr, bfr, (f32x4){0.f, 0.f, 0.f, 0.f}, 0, 0, 0);
    uint2 v; v.x = pack2(acc[0], acc[1]); v.y = pack2(acc[2], acc[3]);
    *(uint2*)&Sld[m16 * SLD_STRIDE + cb + ni * 16 + 4 * q] = v;
  }
  __syncthreads();

  // ---- write S tile to HBM (CSR-ordered rows; consumed by node_z) ----
  {
    const int row = t >> 4, cbase = (t & 15) * 8;
#pragma unroll
    for (int j = 0; j < 8; ++j) {
      uint4 v = *(const uint4*)&Sld[row * SLD_STRIDE + cbase + 128 * j];
      *(uint4*)(S + (size_t)(p0 + row) * 1024 + cbase + 128 * j) = v;
    }
  }

  // ---- phase 2: scores, 2 batches of 8 positions ----
  const int c0 = 4 * t;
  float4 wav = *(const float4*)(Wa + c0);
  const bool lact = (t < 150);
  float4 walv = {0, 0, 0, 0};
  if (lact) walv = *(const float4*)(Wal + c0);
  const float ba0 = ba[0], bal0 = bal[0];

#pragma unroll 1
  for (int bb = 0; bb < 2; ++bb) {
    const int eb = 8 * bb;
    int ss[8], dd[8];
    {
      int4 a4 = *(const int4*)(srcs + p0 + eb);
      int4 b4 = *(const int4*)(srcs + p0 + eb + 4);
      ss[0] = a4.x; ss[1] = a4.y; ss[2] = a4.z; ss[3] = a4.w;
      ss[4] = b4.x; ss[5] = b4.y; ss[6] = b4.z; ss[7] = b4.w;
      int4 c4 = *(const int4*)(dsts + p0 + eb);
      int4 d4 = *(const int4*)(dsts + p0 + eb + 4);
      dd[0] = c4.x; dd[1] = c4.y; dd[2] = c4.z; dd[3] = c4.w;
      dd[4] = d4.x; dd[5] = d4.y; dd[6] = d4.z; dd[7] = d4.w;
    }

    float pf[8], pl[8];
#pragma unroll
    for (int i = 0; i < 8; ++i) {
      uint2 us = *(const uint2*)&Sld[(eb + i) * SLD_STRIDE + c0];
      float4 sv = cvt2x(us);
      float4 p1 = ld4b(P + (size_t)ss[i] * 2048 + c0);
      float4 p2 = ld4b(P + (size_t)dd[i] * 2048 + 1024 + c0);
      float acc = 0.f;
      acc = fmaf(fmaxf(p1.x + p2.x + sv.x, 0.f), wav.x, acc);
      acc = fmaf(fmaxf(p1.y + p2.y + sv.y, 0.f), wav.y, acc);
      acc = fmaf(fmaxf(p1.z + p2.z + sv.z, 0.f), wav.z, acc);
      acc = fmaf(fmaxf(p1.w + p2.w + sv.w, 0.f), wav.w, acc);
      pf[i] = acc;

      float accl = 0.f;
      if (lact) {
        float4 q1 = ld4b(Q + (size_t)ss[i] * 1280 + c0);
        float4 q2 = ld4b(Q + (size_t)dd[i] * 1280 + 600 + c0);
        accl = fmaf(fmaxf(q1.x + q2.x, 0.f), walv.x, accl);
        accl = fmaf(fmaxf(q1.y + q2.y, 0.f), walv.y, accl);
        accl = fmaf(fmaxf(q1.z + q2.z, 0.f), walv.z, accl);
        accl = fmaf(fmaxf(q1.w + q2.w, 0.f), walv.w, accl);
      }
      pl[i] = accl;
    }

#pragma unroll
    for (int i = 0; i < 8; ++i) {
#pragma unroll
      for (int o = 32; o > 0; o >>= 1) {
        pf[i] += __shfl_down(pf[i], o, 64);
        pl[i] += __shfl_down(pl[i], o, 64);
      }
    }
    if (lane == 0) {
#pragma unroll
      for (int i = 0; i < 8; ++i) { shf[i][w] = pf[i]; shl[i][w] = pl[i]; }
    }
    __syncthreads();
    if (t < 8)
      af[p0 + eb + t] = shf[t][0] + shf[t][1] + shf[t][2] + shf[t][3] + ba0;
    if (t >= 64 && t < 72) {
      const int i = t & 7;
      afl[p0 + eb + i] = shl[i][0] + shl[i][1] + shl[i][2] + shl[i][3] + bal0;
    }
    __syncthreads();  // shf/shl reused by next batch
  }
}

//---------------------------------------------------------------------
// Edge scores v11 (FALLBACK when workspace too small for S)
//---------------------------------------------------------------------
__global__ __launch_bounds__(256)
void gnn11_edge_score(const int* __restrict__ src, const int* __restrict__ dst,
                      const float* __restrict__ s_f, const float* __restrict__ We,
                      const float* __restrict__ be, const float* __restrict__ Wa,
                      const float* __restrict__ ba, const float* __restrict__ bel,
                      const float* __restrict__ Wal, const float* __restrict__ bal,
                      const bf16* __restrict__ P, const bf16* __restrict__ Q,
                      float* __restrict__ af, float* __restrict__ afl)
{
  const int t = threadIdx.x;
  const int lane = t & 63, w = t >> 6;
  const int c0 = 4 * t;
  const int e0 = blockIdx.x * 8;

  float wef[16][4];
#pragma unroll
  for (int k = 0; k < 16; ++k) {
    float4 v = *(const float4*)(We + (size_t)(1024 + k) * 1024 + c0);
    wef[k][0] = v.x; wef[k][1] = v.y; wef[k][2] = v.z; wef[k][3] = v.w;
  }
  float4 bev = *(const float4*)(be + c0);
  float4 wav = *(const float4*)(Wa + c0);
  const bool lact = (t < 150);
  float4 belv = {0, 0, 0, 0}, walv = {0, 0, 0, 0};
  if (lact) { belv = *(const float4*)(bel + c0); walv = *(const float4*)(Wal + c0); }

  int ss[8], dd[8];
  {
    int4 a = *(const int4*)(src + e0);
    int4 b = *(const int4*)(src + e0 + 4);
    ss[0] = a.x; ss[1] = a.y; ss[2] = a.z; ss[3] = a.w;
    ss[4] = b.x; ss[5] = b.y; ss[6] = b.z; ss[7] = b.w;
    int4 c = *(const int4*)(dst + e0);
    int4 d = *(const int4*)(dst + e0 + 4);
    dd[0] = c.x; dd[1] = c.y; dd[2] = c.z; dd[3] = c.w;
    dd[4] = d.x; dd[5] = d.y; dd[6] = d.z; dd[7] = d.w;
  }

  float pf[8], pl[8];

#pragma unroll
  for (int i = 0; i < 8; ++i) {
    const int e = e0 + i;
    float sfv[16];
    {
      const float4* sp = (const float4*)(s_f + (size_t)e * 16);
      float4 s0 = sp[0], s1 = sp[1], s2 = sp[2], s3 = sp[3];
      sfv[0] = s0.x; sfv[1] = s0.y; sfv[2] = s0.z; sfv[3] = s0.w;
      sfv[4] = s1.x; sfv[5] = s1.y; sfv[6] = s1.z; sfv[7] = s1.w;
      sfv[8] = s2.x; sfv[9] = s2.y; sfv[10] = s2.z; sfv[11] = s2.w;
      sfv[12] = s3.x; sfv[13] = s3.y; sfv[14] = s3.z; sfv[15] = s3.w;
    }
    float4 p1 = ld4b(P + (size_t)ss[i] * 2048 + c0);
    float4 p2 = ld4b(P + (size_t)dd[i] * 2048 + 1024 + c0);
    float pv[4] = {p1.x + p2.x + bev.x, p1.y + p2.y + bev.y,
                   p1.z + p2.z + bev.z, p1.w + p2.w + bev.w};
    float acc = 0.f;
#pragma unroll
    for (int j = 0; j < 4; ++j) {
      float v = pv[j];
#pragma unroll
      for (int k = 0; k < 16; ++k) v = fmaf(sfv[k], wef[k][j], v);
      acc = fmaf(fmaxf(v, 0.f), (&wav.x)[j], acc);
    }
    pf[i] = acc;

    float accl = 0.f;
    if (lact) {
      float4 q1 = ld4b(Q + (size_t)ss[i] * 1280 + c0);
      float4 q2 = ld4b(Q + (size_t)dd[i] * 1280 + 600 + c0);
      float qv[4] = {q1.x + q2.x + belv.x, q1.y + q2.y + belv.y,
                     q1.z + q2.z + belv.z, q1.w + q2.w + belv.w};
#pragma unroll
      for (int j = 0; j < 4; ++j)
        accl = fmaf(fmaxf(qv[j], 0.f), (&walv.x)[j], accl);
    }
    pl[i] = accl;
  }

  __shared__ float shf[8][4], shl[8][4];
#pragma unroll
  for (int i = 0; i < 8; ++i) {
#pragma unroll
    for (int o = 32; o > 0; o >>= 1) {
      pf[i] += __shfl_down(pf[i], o, 64);
      pl[i] += __shfl_down(pl[i], o, 64);
    }
  }
  if (lane == 0) {
#pragma unroll
    for (int i = 0; i < 8; ++i) { shf[i][w] = pf[i]; shl[i][w] = pl[i]; }
  }
  __syncthreads();
  if (t < 8)
    af[e0 + t] = shf[t][0] + shf[t][1] + shf[t][2] + shf[t][3] + ba[0];
  if (t >= 64 && t < 72) {
    const int i = t & 7;
    afl[e0 + i] = shl[i][0] + shl[i][1] + shl[i][2] + shl[i][3] + bal[0];
  }
}

//---------------------------------------------------------------------
// Per-node softmax. v14: position-indexed af/afl (sequential reads).
//---------------------------------------------------------------------
__global__ __launch_bounds__(256)
void gnn14_alpha(const int* __restrict__ off, float* __restrict__ af,
                 float* __restrict__ afl)
{
  const int n = blockIdx.x * 256 + threadIdx.x;
  if (n >= N_NODES) return;
  const int base = off[n];
  const int deg = off[n + 1] - base;
  float m = -1e30f, ml = -1e30f;
  for (int i = 0; i < deg; ++i) {
    m = fmaxf(m, af[base + i]);
    ml = fmaxf(ml, afl[base + i]);
  }
  float den = 0.f, denl = 0.f;
  for (int i = 0; i < deg; ++i) {
    den += expf(af[base + i] - m);
    denl += expf(afl[base + i] - ml);
  }
  float inv = (den > 0.f) ? 1.f / den : 0.f;
  float invl = (denl > 0.f) ? 1.f / denl : 0.f;
  for (int i = 0; i < deg; ++i) {
    af[base + i] = expf(af[base + i] - m) * inv;
    afl[base + i] = expf(afl[base + i] - ml) * invl;
  }
}

// v6 fallback (edge-id indexed via elist)
__global__ __launch_bounds__(256)
void gnn6_alpha(const int* __restrict__ off, const int* __restrict__ elist,
                float* __restrict__ af, float* __restrict__ afl)
{
  const int n = blockIdx.x * 256 + threadIdx.x;
  if (n >= N_NODES) return;
  const int base = off[n];
  const int deg = off[n + 1] - base;
  float m = -1e30f, ml = -1e30f;
  for (int i = 0; i < deg; ++i) {
    int e = elist[base + i];
    m = fmaxf(m, af[e]);
    ml = fmaxf(ml, afl[e]);
  }
  float den = 0.f, denl = 0.f;
  for (int i = 0; i < deg; ++i) {
    int e = elist[base + i];
    den += expf(af[e] - m);
    denl += expf(afl[e] - ml);
  }
  float inv = (den > 0.f) ? 1.f / den : 0.f;
  float invl = (denl > 0.f) ? 1.f / denl : 0.f;
  for (int i = 0; i < deg; ++i) {
    int e = elist[base + i];
    af[e] = expf(af[e] - m) * inv;
    afl[e] = expf(afl[e] - ml) * invl;
  }
}

//---------------------------------------------------------------------
// node_z v14: CSR-ordered — S rows, af/afl sequential; src via srcs.
//---------------------------------------------------------------------
__global__ __launch_bounds__(256)
void gnn14_node_z(const int* __restrict__ off, const int* __restrict__ srcs,
                  const float* __restrict__ af, const float* __restrict__ afl,
                  const bf16* __restrict__ nf_bf, const bf16* __restrict__ w2v_pad,
                  const bf16* __restrict__ S, const bf16* __restrict__ P,
                  bf16* __restrict__ zf, bf16* __restrict__ zfl_pad)
{
  const int node = blockIdx.x;
  const int t = threadIdx.x;
  const int c0 = 4 * t;
  const int base = off[node];
  const int deg = off[node + 1] - base;

  float4 p2v = ld4b(P + (size_t)node * 2048 + 1024 + c0);  // be folded in
  const float p2[4] = {p2v.x, p2v.y, p2v.z, p2v.w};

  float acc[4] = {0.f, 0.f, 0.f, 0.f};
  float accl[4] = {0.f, 0.f, 0.f, 0.f};
  const bool lact = (t < 75);

  for (int i = 0; i < deg; ++i) {
    const int pidx = base + i;
    const int s = srcs[pidx];
    const float wgt = af[pidx];
    const float wl = afl[pidx];

    float4 sv = ld4b(S + (size_t)pidx * 1024 + c0);
    float4 p1 = ld4b(P + (size_t)s * 2048 + c0);
    float4 nf4 = ld4b(nf_bf + (size_t)s * 1024 + c0);
    const float p1a[4] = {p1.x, p1.y, p1.z, p1.w};
    const float sva[4] = {sv.x, sv.y, sv.z, sv.w};
    const float nfa[4] = {nf4.x, nf4.y, nf4.z, nf4.w};
#pragma unroll
    for (int j = 0; j < 4; ++j) {
      float ef = fmaxf(p1a[j] + p2[j] + sva[j], 0.f);
      acc[j] = fmaf(wgt, nfa[j] + ef, acc[j]);
    }
    if (lact) {
      float4 wv = ld4b(w2v_pad + (size_t)s * 320 + c0);
      accl[0] = fmaf(wl, wv.x, accl[0]);
      accl[1] = fmaf(wl, wv.y, accl[1]);
      accl[2] = fmaf(wl, wv.z, accl[2]);
      accl[3] = fmaf(wl, wv.w, accl[3]);
    }
  }
  st4b(zf + (size_t)node * 1024 + c0, acc[0], acc[1], acc[2], acc[3]);
  if (lact)
    st4b(zfl_pad + (size_t)node * 320 + c0, accl[0], accl[1], accl[2], accl[3]);
  else if (t < 80)
    st4b(zfl_pad + (size_t)node * 320 + c0, 0.f, 0.f, 0.f, 0.f);
}

//---------------------------------------------------------------------
// node_z v9 (FALLBACK when workspace too small for S)
//---------------------------------------------------------------------
__global__ __launch_bounds__(256)
void gnn9_node_z(const int* __restrict__ off, const int* __restrict__ elist,
                 const int* __restrict__ src, const float* __restrict__ af,
                 const float* __restrict__ afl, const bf16* __restrict__ nf_bf,
                 const bf16* __restrict__ w2v_pad, const float* __restrict__ s_f,
                 const float* __restrict__ We, const float* __restrict__ be,
                 const bf16* __restrict__ P, bf16* __restrict__ zf,
                 bf16* __restrict__ zfl_pad)
{
  const int node = blockIdx.x;
  const int t = threadIdx.x;
  const int c0 = 4 * t;
  const int base = off[node];
  const int deg = off[node + 1] - base;

  float wef[16][4];
#pragma unroll
  for (int k = 0; k < 16; ++k) {
    float4 v = *(const float4*)(We + (size_t)(1024 + k) * 1024 + c0);
    wef[k][0] = v.x; wef[k][1] = v.y; wef[k][2] = v.z; wef[k][3] = v.w;
  }
  float4 p2v = ld4b(P + (size_t)node * 2048 + 1024 + c0);
  float4 bev = *(const float4*)(be + c0);
  const float p2[4] = {p2v.x + bev.x, p2v.y + bev.y, p2v.z + bev.z, p2v.w + bev.w};

  float acc[4] = {0.f, 0.f, 0.f, 0.f};
  float accl[4] = {0.f, 0.f, 0.f, 0.f};
  const bool lact = (t < 75);

  for (int i = 0; i < deg; ++i) {
    const int e = elist[base + i];
    const int s = src[e];
    const float wgt = af[e];
    const float wl = afl[e];

    float sfv[16];
    {
      const float4* sp = (const float4*)(s_f + (size_t)e * 16);
      float4 s0 = sp[0], s1 = sp[1], s2 = sp[2], s3 = sp[3];
      sfv[0] = s0.x; sfv[1] = s0.y; sfv[2] = s0.z; sfv[3] = s0.w;
      sfv[4] = s1.x; sfv[5] = s1.y; sfv[6] = s1.z; sfv[7] = s1.w;
      sfv[8] = s2.x; sfv[9] = s2.y; sfv[10] = s2.z; sfv[11] = s2.w;
      sfv[12] = s3.x; sfv[13] = s3.y; sfv[14] = s3.z; sfv[15] = s3.w;
    }

    float4 p1 = ld4b(P + (size_t)s * 2048 + c0);
    float4 nf4 = ld4b(nf_bf + (size_t)s * 1024 + c0);
    const float p1a[4] = {p1.x, p1.y, p1.z, p1.w};
    const float nfa[4] = {nf4.x, nf4.y, nf4.z, nf4.w};
#pragma unroll
    for (int j = 0; j < 4; ++j) {
      float ef = p1a[j] + p2[j];
#pragma unroll
      for (int k = 0; k < 16; ++k) ef = fmaf(sfv[k], wef[k][j], ef);
      ef = fmaxf(ef, 0.f);
      acc[j] = fmaf(wgt, nfa[j] + ef, acc[j]);
    }
    if (lact) {
      float4 wv = ld4b(w2v_pad + (size_t)s * 320 + c0);
      accl[0] = fmaf(wl, wv.x, accl[0]);
      accl[1] = fmaf(wl, wv.y, accl[1]);
      accl[2] = fmaf(wl, wv.z, accl[2]);
      accl[3] = fmaf(wl, wv.w, accl[3]);
    }
  }
  st4b(zf + (size_t)node * 1024 + c0, acc[0], acc[1], acc[2], acc[3]);
  if (lact)
    st4b(zfl_pad + (size_t)node * 320 + c0, accl[0], accl[1], accl[2], accl[3]);
  else if (t < 80)
    st4b(zfl_pad + (size_t)node * 320 + c0, 0.f, 0.f, 0.f, 0.f);
}

//=====================================================================
extern "C" void kernel_launch(void* const* d_in, const int* in_sizes, int n_in,
                              void* d_out, int out_size, void* d_ws, size_t ws_size,
                              hipStream_t stream)
{
  (void)hipGetLastError();
  if (n_in != 17) { (void)hipMemsetAsync(d_out, 0x41, 4096, stream); return; }

  const float* n_f = (const float*)d_in[0];
  const float* w2v = (const float*)d_in[1];
  const float* s_f = (const float*)d_in[2];
  const int*   src = (const int*)d_in[3];
  const int*   dst = (const int*)d_in[4];
  const float* We  = (const float*)d_in[5];
  const float* be  = (const float*)d_in[6];
  const float* Wel = (const float*)d_in[7];
  const float* bel = (const float*)d_in[8];
  const float* Wa  = (const float*)d_in[9];
  const float* ba  = (const float*)d_in[10];
  const float* Wal = (const float*)d_in[11];
  const float* bal = (const float*)d_in[12];
  const float* Wn  = (const float*)d_in[13];
  const float* bn  = (const float*)d_in[14];
  const float* Wnl = (const float*)d_in[15];
  const float* bnl = (const float*)d_in[16];
  float* out  = (float*)d_out;
  float* out2 = out + OUT0_ELEMS;

  char* ws = (char*)d_ws;
  size_t o = 0;
  auto alloc = [&](size_t bytes) -> void* {
    void* p = ws + o; o += bytes; o = (o + 255) & ~(size_t)255; return p;
  };
  bf16* P        = (bf16*)alloc((size_t)N_NODES * 2048 * 2);
  bf16* Q        = (bf16*)alloc((size_t)N_NODES * 1280 * 2);
  bf16* zf       = (bf16*)alloc((size_t)N_NODES * 1024 * 2);
  bf16* zfl_pad  = (bf16*)alloc((size_t)N_NODES * 320 * 2);
  bf16* nf_bf    = (bf16*)alloc((size_t)N_NODES * 1024 * 2);
  bf16* w2v_pad  = (bf16*)alloc((size_t)N_NODES * 320 * 2);
  bf16* WeT      = (bf16*)alloc((size_t)2048 * 1024 * 2);
  bf16* WnT      = (bf16*)alloc((size_t)1024 * 2048 * 2);
  bf16* WelT     = (bf16*)alloc((size_t)1280 * 320 * 2);
  bf16* WnlT     = (bf16*)alloc((size_t)384 * 640 * 2);
  float* af      = (float*)alloc((size_t)N_EDGES * 4);
  float* afl     = (float*)alloc((size_t)N_EDGES * 4);
  int* cnt       = (int*)alloc((size_t)N_NODES * 4);
  int* offs      = (int*)alloc((size_t)(N_NODES + 1) * 4);
  int* cur       = (int*)alloc((size_t)N_NODES * 4);
  int* elist     = (int*)alloc((size_t)N_EDGES * 4);
  size_t base_end = o;
  if (base_end > ws_size) { (void)hipMemsetAsync(d_out, 0x42, 4096, stream); return; }

  // Extended (CSR-sorted S path) allocations — used only if ws fits.
  bf16* sfp     = (bf16*)alloc((size_t)N_EDGES * 32 * 2);
  bf16* WeTtail = (bf16*)alloc((size_t)1024 * 32 * 2);
  bf16* S       = (bf16*)alloc((size_t)N_EDGES * 1024 * 2);
  int* srcs     = (int*)alloc((size_t)N_EDGES * 4);
  int* dsts     = (int*)alloc((size_t)N_EDGES * 4);
  const bool useS = (o <= ws_size);

  gnn6_zero<<<N_NODES / 256, 256, 0, stream>>>(cnt, N_NODES);
  gnn7_cvt<<<(N_NODES * 1024 / 8 + 255) / 256, 256, 0, stream>>>(n_f, nf_bf,
                                                                 N_NODES * 1024 / 8);
  gnn8_pad_w2v<<<(N_NODES * 80 + 255) / 256, 256, 0, stream>>>(w2v, w2v_pad);
  { dim3 g(32, 64); gnn10_t_We<<<g, 256, 0, stream>>>(We, WeT); }
  { dim3 g(64, 32); gnn10_t_Wn<<<g, 256, 0, stream>>>(Wn, WnT); }
  { dim3 g(10, 40); gnn10_t_Wel<<<g, 256, 0, stream>>>(Wel, WelT); }
  { dim3 g(20, 12); gnn10_t_Wnl<<<g, 256, 0, stream>>>(Wnl, WnlT); }

  // CSR build first (needed by the sorted scoring path).
  gnn6_count<<<N_EDGES / 256, 256, 0, stream>>>(dst, cnt);
  gnn6_scan<<<1, 1024, 0, stream>>>(cnt, offs, cur);
  if (useS) {
    gnn14_fill<<<N_EDGES / 256, 256, 0, stream>>>(dst, src, cur, elist, srcs, dsts);
    gnn12_t_Wetail<<<4, 256, 0, stream>>>(We, WeTtail);
    gnn14_sfp<<<N_EDGES / 256, 256, 0, stream>>>(s_f, elist, sfp);
  } else {
    gnn6_fill<<<N_EDGES / 256, 256, 0, stream>>>(dst, cur, elist);
  }

  {
    dim3 g(2048 / 128, N_NODES / 128);
    gnn17_mm_P<<<g, 256, 0, stream>>>(nf_bf, WeT, P, useS ? be : nullptr);
  }
  {
    dim3 g(1280 / 128, N_NODES / 128);
    gnn10_mm_Q<<<g, 256, 0, stream>>>(w2v_pad, WelT, Q, useS ? bel : nullptr);
  }

  if (useS) {
    gnn14_mm_S_score<<<N_EDGES / 16, 256, 0, stream>>>(
        sfp, WeTtail, srcs, dsts, Wa, ba, Wal, bal, P, Q, S, af, afl);
    gnn14_alpha<<<N_NODES / 256, 256, 0, stream>>>(offs, af, afl);
    gnn14_node_z<<<N_NODES, 256, 0, stream>>>(offs, srcs, af, afl, nf_bf,
                                              w2v_pad, S, P, zf, zfl_pad);
  } else {
    gnn11_edge_score<<<N_EDGES / 8, 256, 0, stream>>>(src, dst, s_f, We, be, Wa,
                                                      ba, bel, Wal, bal, P, Q,
                                                      af, afl);
    gnn6_alpha<<<N_NODES / 256, 256, 0, stream>>>(offs, elist, af, afl);
    gnn9_node_z<<<N_NODES, 256, 0, stream>>>(offs, elist, src, af, afl, nf_bf,
                                             w2v_pad, s_f, We, be, P, zf, zfl_pad);
  }

  {
    dim3 g(1024 / 128, N_NODES / 128);
    gnn17_mm_out_n<<<g, 256, 0, stream>>>(nf_bf, zf, WnT, bn, out);
  }
  {
    dim3 g(384 / 128, N_NODES / 128);
    gnn10_mm_out_l<<<g, 256, 0, stream>>>(w2v_pad, zfl_pad, WnlT, bnl, out2);
  }

  if (hipGetLastError() != hipSuccess) (void)hipMemsetAsync(d_out, 0x44, 4096, stream);
}